// Round 2
// baseline (2396.925 us; speedup 1.0000x reference)
//
#include <hip/hip_runtime.h>

#define NHW 1024
#define NB 4
#define DM 256
#define NTOK 4096      // NHW * NB
#define NCIN 272
#define NDFF 1024
#define NEXP 8

__device__ __forceinline__ float4 ld4(const float* p){ return *(const float4*)p; }
__device__ __forceinline__ void st4(float* p, float4 v){ *(float4*)p = v; }

// ---------------- positional embedding ----------------
__global__ void pos_kernel(float* __restrict__ pos){
  int s = blockIdx.x, d = threadIdx.x;
  int row = s >> 5, col = s & 31;
  float base = (d < 128) ? (float)(row + 1) : (float)(col + 1);
  float val = base / (32.0f + 1e-6f) * 6.2831853071795864f;
  int dd = (d < 128) ? d : d - 128;
  int mf = dd >> 1;
  float f = powf(10000.0f, (float)mf * (1.0f/64.0f));
  float a = val / f;
  pos[s*DM + d] = (dd & 1) ? cosf(a) : sinf(a);
}

// ---------------- transposes ----------------
__global__ void tin_kernel(const float* __restrict__ x, float* __restrict__ tok){
  int idx = blockIdx.x*256 + threadIdx.x;
  if (idx >= NTOK*NCIN) return;
  int c = idx % NCIN;
  int n = idx / NCIN;
  int s = n >> 2, b = n & 3;
  tok[idx] = x[((long)(b*NCIN + c))*NHW + s];
}
__global__ void tout_kernel(const float* __restrict__ rec, float* __restrict__ out){
  int idx = blockIdx.x*256 + threadIdx.x;
  if (idx >= NTOK*NCIN) return;
  int s = idx & (NHW-1);
  int bc = idx >> 10;
  int b = bc / NCIN, c = bc % NCIN;
  out[idx] = rec[((long)(s*NB + b))*NCIN + c];
}

// ---------------- elementwise: out[n] = in[.] + pos[s] ----------------
template<int AMODE>   // 0: in indexed by n ; 1: in indexed by s (broadcast over batch)
__global__ __launch_bounds__(256) void addpos_kernel(const float* __restrict__ in,
    const float* __restrict__ pos, float* __restrict__ out){
  int gid = blockIdx.x*256 + threadIdx.x;      // one float4 each; NTOK*DM/4 = 262144
  int n = gid >> 6;
  int d4 = (gid & 63) << 2;
  int s = n >> 2;
  const float* ip = in + (AMODE ? (long)s*DM : (long)n*DM) + d4;
  float4 a = ld4(ip);
  float4 p = ld4(&pos[(long)s*DM + d4]);
  a.x += p.x; a.y += p.y; a.z += p.z; a.w += p.w;
  st4(&out[(long)n*DM + d4], a);
}

// ---------------- generic 64x64 fp32 GEMM: C = A @ op(B) + bias ----------------
// BT=true : B is [N,K] row-major (use B^T)   ; BT=false : B is [K,N] row-major
// GROUPED : per-expert (blockIdx.z = e), rows = cnt[e], compact row base offs[e]
// INDIRECT: A row fetched via map[global_row]
template<bool GROUPED, bool INDIRECT, bool BT, bool RELU>
__global__ __launch_bounds__(256) void gemm_k(
    const float* __restrict__ A, int lda,
    const float* __restrict__ B, int ldb,
    const float* __restrict__ bias,
    float* __restrict__ C, int ldc,
    int M, int N, int K,
    const int* __restrict__ map,
    const int* __restrict__ cnt,
    const int* __restrict__ offs,
    long strideB, int strideBias)
{
  int e = GROUPED ? blockIdx.z : 0;
  int rows = GROUPED ? cnt[e] : M;
  int bm = blockIdx.x, bn = blockIdx.y;
  if (bm*64 >= rows) return;
  int row0 = GROUPED ? offs[e] : 0;
  const float* Bp = GROUPED ? (B + (long)e*strideB) : B;
  const float* biasp = bias ? (GROUPED ? bias + e*strideBias : bias) : nullptr;

  __shared__ float As[32][68];   // [k][m], 68-stride keeps 16B alignment
  __shared__ float Bs[32][68];   // [k][n]

  int tid = threadIdx.x;
  int tm4 = (tid >> 4) << 2;
  int tn4 = (tid & 15) << 2;
  float acc[4][4];
  #pragma unroll
  for (int i=0;i<4;i++)
    #pragma unroll
    for (int j=0;j<4;j++) acc[i][j]=0.f;

  for (int k0 = 0; k0 < K; k0 += 32){
    // ---- stage A (64 rows x 32 k), transposed into LDS ----
    #pragma unroll
    for (int i=0;i<2;i++){
      int fidx = tid*2 + i;
      int r = fidx >> 3;
      int kk4 = (fidx & 7) << 2;
      int grow = bm*64 + r;
      float4 av = make_float4(0.f,0.f,0.f,0.f);
      if (grow < rows && (k0 + kk4) < K){
        int arow = INDIRECT ? map[row0 + grow] : (row0 + grow);
        av = ld4(&A[(long)arow*lda + k0 + kk4]);
      }
      As[kk4+0][r]=av.x; As[kk4+1][r]=av.y; As[kk4+2][r]=av.z; As[kk4+3][r]=av.w;
    }
    // ---- stage B ----
    if (BT){
      #pragma unroll
      for (int i=0;i<2;i++){
        int fidx = tid*2 + i;
        int r = fidx >> 3;
        int kk4 = (fidx & 7) << 2;
        int gcol = bn*64 + r;
        float4 bv = make_float4(0.f,0.f,0.f,0.f);
        if (gcol < N && (k0 + kk4) < K)
          bv = ld4(&Bp[(long)gcol*ldb + k0 + kk4]);
        Bs[kk4+0][r]=bv.x; Bs[kk4+1][r]=bv.y; Bs[kk4+2][r]=bv.z; Bs[kk4+3][r]=bv.w;
      }
    } else {
      #pragma unroll
      for (int i=0;i<2;i++){
        int fidx = tid*2 + i;           // 0..511
        int kk = fidx >> 4;             // 0..31
        int n4 = (fidx & 15) << 2;      // 0..60
        int gn = bn*64 + n4;
        float4 bv = make_float4(0.f,0.f,0.f,0.f);
        if ((k0 + kk) < K && gn < N)
          bv = ld4(&Bp[(long)(k0+kk)*ldb + gn]);
        st4(&Bs[kk][n4], bv);
      }
    }
    __syncthreads();
    #pragma unroll
    for (int kk=0; kk<32; kk++){
      float4 a = ld4(&As[kk][tm4]);
      float4 b = ld4(&Bs[kk][tn4]);
      acc[0][0]+=a.x*b.x; acc[0][1]+=a.x*b.y; acc[0][2]+=a.x*b.z; acc[0][3]+=a.x*b.w;
      acc[1][0]+=a.y*b.x; acc[1][1]+=a.y*b.y; acc[1][2]+=a.y*b.z; acc[1][3]+=a.y*b.w;
      acc[2][0]+=a.z*b.x; acc[2][1]+=a.z*b.y; acc[2][2]+=a.z*b.z; acc[2][3]+=a.z*b.w;
      acc[3][0]+=a.w*b.x; acc[3][1]+=a.w*b.y; acc[3][2]+=a.w*b.z; acc[3][3]+=a.w*b.w;
    }
    __syncthreads();
  }
  int gn = bn*64 + tn4;
  if (gn >= N) return;                  // N is always a multiple of 4 here
  float4 bv = make_float4(0.f,0.f,0.f,0.f);
  if (biasp) bv = ld4(&biasp[gn]);
  #pragma unroll
  for (int i=0;i<4;i++){
    int grow = bm*64 + tm4 + i;
    if (grow < rows){
      float4 cv = make_float4(acc[i][0]+bv.x, acc[i][1]+bv.y, acc[i][2]+bv.z, acc[i][3]+bv.w);
      if (RELU){
        cv.x=fmaxf(cv.x,0.f); cv.y=fmaxf(cv.y,0.f); cv.z=fmaxf(cv.z,0.f); cv.w=fmaxf(cv.w,0.f);
      }
      st4(&C[(long)(row0+grow)*ldc + gn], cv);
    }
  }
}

// ---------------- flash attention, fp32, dh=32, S=T=1024 ----------------
// grid (16 qtiles, 32 bh); block 256.  4 lanes per query row, each over 1/4 of keys.
__global__ __launch_bounds__(256) void attn_kernel(const float* __restrict__ Q,
    const float* __restrict__ Kb, const float* __restrict__ Vb, float* __restrict__ O)
{
  __shared__ float Ks[64][36];
  __shared__ float Vs[64][36];
  int qt = blockIdx.x, bh = blockIdx.y;
  int b = bh >> 3, h = bh & 7;
  int tid = threadIdx.x;
  int rl = tid >> 2, sub = tid & 3;
  int qpos = qt*64 + rl;
  long qrow = ((long)(qpos*NB + b))*DM + h*32;
  const float scale = 0.17677669529663687f;   // 1/sqrt(32)
  float q[32], o[32];
  float m = -1e30f, l = 0.f;
  #pragma unroll
  for (int d=0; d<32; d+=4){
    float4 t = ld4(&Q[qrow + d]);
    q[d]=t.x*scale; q[d+1]=t.y*scale; q[d+2]=t.z*scale; q[d+3]=t.w*scale;
    o[d]=0.f; o[d+1]=0.f; o[d+2]=0.f; o[d+3]=0.f;
  }
  for (int kt=0; kt<16; kt++){
    __syncthreads();
    #pragma unroll
    for (int i=0;i<2;i++){
      int fidx = tid*2 + i;
      int r = fidx >> 3, d4 = (fidx & 7) << 2;
      long g = ((long)((kt*64 + r)*NB + b))*DM + h*32 + d4;
      st4(&Ks[r][d4], ld4(&Kb[g]));
      st4(&Vs[r][d4], ld4(&Vb[g]));
    }
    __syncthreads();
    float s[16];
    #pragma unroll
    for (int j=0;j<16;j++){
      int c = (j<<2) + sub;               // conflict-free: 4 subs hit distinct banks
      float acc = 0.f;
      #pragma unroll
      for (int d=0; d<32; d+=4){
        float4 kv = ld4(&Ks[c][d]);
        acc += q[d]*kv.x + q[d+1]*kv.y + q[d+2]*kv.z + q[d+3]*kv.w;
      }
      s[j] = acc;
    }
    float tm = s[0];
    #pragma unroll
    for (int j=1;j<16;j++) tm = fmaxf(tm, s[j]);
    float M = fmaxf(m, tm);
    float alpha = __expf(m - M);
    l *= alpha;
    #pragma unroll
    for (int d=0; d<32; d++) o[d] *= alpha;
    #pragma unroll
    for (int j=0;j<16;j++){
      float p = __expf(s[j] - M);
      l += p;
      int c = (j<<2) + sub;
      #pragma unroll
      for (int d=0; d<32; d+=4){
        float4 vv = ld4(&Vs[c][d]);
        o[d]   += p*vv.x; o[d+1] += p*vv.y; o[d+2] += p*vv.z; o[d+3] += p*vv.w;
      }
    }
    m = M;
  }
  // merge the 4 partial states (key-range split) across lanes sub=0..3
  #pragma unroll
  for (int mask=1; mask<=2; mask<<=1){
    float m2 = __shfl_xor(m, mask);
    float l2 = __shfl_xor(l, mask);
    float M = fmaxf(m, m2);
    float a1 = __expf(m - M), a2 = __expf(m2 - M);
    l = a1*l + a2*l2;
    #pragma unroll
    for (int d=0; d<32; d++){
      float o2 = __shfl_xor(o[d], mask);
      o[d] = a1*o[d] + a2*o2;
    }
    m = M;
  }
  float inv = 1.f/l;
  float4 t0, t1;
  switch(sub){
    case 0: t0=make_float4(o[0],o[1],o[2],o[3]);     t1=make_float4(o[4],o[5],o[6],o[7]);     break;
    case 1: t0=make_float4(o[8],o[9],o[10],o[11]);   t1=make_float4(o[12],o[13],o[14],o[15]); break;
    case 2: t0=make_float4(o[16],o[17],o[18],o[19]); t1=make_float4(o[20],o[21],o[22],o[23]); break;
    default:t0=make_float4(o[24],o[25],o[26],o[27]); t1=make_float4(o[28],o[29],o[30],o[31]); break;
  }
  t0.x*=inv; t0.y*=inv; t0.z*=inv; t0.w*=inv;
  t1.x*=inv; t1.y*=inv; t1.z*=inv; t1.w*=inv;
  st4(&O[qrow + sub*8], t0);
  st4(&O[qrow + sub*8 + 4], t1);
}

// ---------------- fused add + LayerNorm (wave per row) ----------------
__device__ __forceinline__ float wave_sum(float v){
  #pragma unroll
  for (int m=1; m<64; m<<=1) v += __shfl_xor(v, m);
  return v;
}

template<int AMODE>  // 0: A[row] ; 1: A[row>>2] (broadcast over batch, e.g. learned_embed)
__global__ __launch_bounds__(256) void add_ln_kernel(const float* __restrict__ A,
    const float* __restrict__ Bv, const float* __restrict__ g, const float* __restrict__ beta,
    float* __restrict__ out)
{
  int row = blockIdx.x*4 + (threadIdx.x >> 6);
  int lane = threadIdx.x & 63;
  const float* ap = A + (AMODE ? (long)(row>>2)*DM : (long)row*DM);
  float4 a = ld4(&ap[lane*4]);
  float4 b = ld4(&Bv[(long)row*DM + lane*4]);
  a.x+=b.x; a.y+=b.y; a.z+=b.z; a.w+=b.w;
  float sum = wave_sum(a.x+a.y+a.z+a.w);
  float sq  = wave_sum(a.x*a.x + a.y*a.y + a.z*a.z + a.w*a.w);
  float mean = sum * (1.f/DM);
  float var  = sq * (1.f/DM) - mean*mean;
  float inv = 1.0f / sqrtf(var + 1e-5f);
  float4 gg = ld4(&g[lane*4]);
  float4 bb = ld4(&beta[lane*4]);
  float4 ov;
  ov.x = (a.x-mean)*inv*gg.x + bb.x;
  ov.y = (a.y-mean)*inv*gg.y + bb.y;
  ov.z = (a.z-mean)*inv*gg.z + bb.z;
  ov.w = (a.w-mean)*inv*gg.w + bb.w;
  st4(&out[(long)row*DM + lane*4], ov);
}

// out = LN(base + s0*y[r0] + s1*y[r1])
__global__ __launch_bounds__(256) void moe_ln_kernel(const float* __restrict__ base,
    const float* __restrict__ yg, const float* __restrict__ scores, const int* __restrict__ rpos,
    const float* __restrict__ g, const float* __restrict__ beta, float* __restrict__ out)
{
  int row = blockIdx.x*4 + (threadIdx.x >> 6);
  int lane = threadIdx.x & 63;
  float s0 = scores[row*2], s1 = scores[row*2+1];
  int r0 = rpos[row*2], r1 = rpos[row*2+1];
  float4 a  = ld4(&base[(long)row*DM + lane*4]);
  float4 y0 = ld4(&yg[(long)r0*DM + lane*4]);
  float4 y1 = ld4(&yg[(long)r1*DM + lane*4]);
  a.x += s0*y0.x + s1*y1.x;
  a.y += s0*y0.y + s1*y1.y;
  a.z += s0*y0.z + s1*y1.z;
  a.w += s0*y0.w + s1*y1.w;
  float sum = wave_sum(a.x+a.y+a.z+a.w);
  float sq  = wave_sum(a.x*a.x + a.y*a.y + a.z*a.z + a.w*a.w);
  float mean = sum * (1.f/DM);
  float var  = sq * (1.f/DM) - mean*mean;
  float inv = 1.0f / sqrtf(var + 1e-5f);
  float4 gg = ld4(&g[lane*4]);
  float4 bb = ld4(&beta[lane*4]);
  float4 ov;
  ov.x = (a.x-mean)*inv*gg.x + bb.x;
  ov.y = (a.y-mean)*inv*gg.y + bb.y;
  ov.z = (a.z-mean)*inv*gg.z + bb.z;
  ov.w = (a.w-mean)*inv*gg.w + bb.w;
  st4(&out[(long)row*DM + lane*4], ov);
}

// ---------------- MoE gate: logits, top-2, softmax, counts ----------------
__global__ __launch_bounds__(256) void gate_kernel(const float* __restrict__ X,
    const float* __restrict__ GW, const float* __restrict__ GB,
    float* __restrict__ scores, int* __restrict__ topi, int* __restrict__ cnt)
{
  int row = blockIdx.x*4 + (threadIdx.x >> 6);
  int lane = threadIdx.x & 63;
  float4 x = ld4(&X[(long)row*DM + lane*4]);
  float lg[8];
  #pragma unroll
  for (int e=0; e<8; e++){
    float4 wv = ld4(&GW[e*DM + lane*4]);
    lg[e] = x.x*wv.x + x.y*wv.y + x.z*wv.z + x.w*wv.w;
  }
  #pragma unroll
  for (int mask=1; mask<64; mask<<=1){
    #pragma unroll
    for (int e=0; e<8; e++) lg[e] += __shfl_xor(lg[e], mask);
  }
  #pragma unroll
  for (int e=0; e<8; e++) lg[e] += GB[e];
  int i0 = 0; float v0 = lg[0];
  #pragma unroll
  for (int e=1; e<8; e++) if (lg[e] > v0){ v0 = lg[e]; i0 = e; }
  int i1 = -1; float v1 = -1e30f;
  #pragma unroll
  for (int e=0; e<8; e++) if (e != i0 && lg[e] > v1){ v1 = lg[e]; i1 = e; }
  if (lane == 0){
    float ee = expf(v1 - v0);         // v1 <= v0
    float inv = 1.f/(1.f + ee);
    scores[row*2]   = inv;
    scores[row*2+1] = ee*inv;
    topi[row*2]   = i0;
    topi[row*2+1] = i1;
    atomicAdd(&cnt[i0], 1);
    atomicAdd(&cnt[i1], 1);
  }
}

__global__ void offs_kernel(const int* __restrict__ cnt, int* __restrict__ offs,
                            int* __restrict__ cnt2){
  if (threadIdx.x == 0){
    int o = 0;
    for (int e=0; e<8; e++){ offs[e] = o; o += cnt[e]; cnt2[e] = 0; }
  }
}

__global__ void assign_kernel(const int* __restrict__ topi, const int* __restrict__ offs,
    int* __restrict__ cnt2, int* __restrict__ map, int* __restrict__ rpos)
{
  int n = blockIdx.x*256 + threadIdx.x;
  if (n >= NTOK) return;
  for (int j=0; j<2; j++){
    int e = topi[n*2+j];
    int slot = atomicAdd(&cnt2[e], 1);
    int r = offs[e] + slot;
    map[r] = n;
    rpos[n*2+j] = r;
  }
}

__global__ void zero_ints(int* p, int n){
  int i = blockIdx.x*256 + threadIdx.x;
  if (i < n) p[i] = 0;
}

// =================================================================
extern "C" void kernel_launch(void* const* d_in, const int* in_sizes, int n_in,
                              void* d_out, int out_size, void* d_ws, size_t ws_size,
                              hipStream_t stream)
{
  const float* x      = (const float*)d_in[0];
  const float* Wi     = (const float*)d_in[1];
  const float* bi     = (const float*)d_in[2];
  const float* le     = (const float*)d_in[3];
  const float* Wqkv_s = (const float*)d_in[4];
  const float* bqkv_s = (const float*)d_in[5];
  const float* Wo_s   = (const float*)d_in[6];
  const float* bo_s   = (const float*)d_in[7];
  const float* Wqkv_c = (const float*)d_in[8];
  const float* bqkv_c = (const float*)d_in[9];
  const float* Wo_c   = (const float*)d_in[10];
  const float* bo_c   = (const float*)d_in[11];
  const float* ln_g   = (const float*)d_in[12];
  const float* ln_b   = (const float*)d_in[13];
  const float* gw1    = (const float*)d_in[14];
  const float* gb1    = (const float*)d_in[15];
  const float* W1a    = (const float*)d_in[16];
  const float* b1a    = (const float*)d_in[17];
  const float* W2a    = (const float*)d_in[18];
  const float* b2a    = (const float*)d_in[19];
  const float* gw2    = (const float*)d_in[20];
  const float* gb2    = (const float*)d_in[21];
  const float* W1b    = (const float*)d_in[22];
  const float* b1b    = (const float*)d_in[23];
  const float* W2b    = (const float*)d_in[24];
  const float* b2b    = (const float*)d_in[25];
  const float* Wout   = (const float*)d_in[26];
  const float* bout   = (const float*)d_in[27];

  float* w = (float*)d_ws;
  const long SZ = 1048576;            // NTOK*DM
  float* pos  = w;                    // 262144
  float* src  = pos  + 262144;
  float* t2s  = src  + SZ;
  float* tgtA = t2s  + SZ;
  float* dec  = tgtA + SZ;
  float* od   = dec  + SZ;
  float* od2  = od   + SZ;
  float* q    = od2  + SZ;
  float* k    = q    + SZ;
  float* v    = k    + SZ;            // also reused as t2c
  float* ao   = v    + SZ;
  float* yg   = ao   + SZ;            // 8192*256 = 2097152
  float* scores = yg + 2097152;       // 8192
  float* R    = scores + 8192;        // big overlay region: 8388608 floats
  float* hg   = R;                    // 8192*1024
  float* tok  = R;                    // dead before encp written
  float* encp = R;
  float* tp   = R + SZ;               // tgt0p / tgtAp (dead before MoE)
  float* decp = R + 2*SZ;             // dead before MoE
  float* rec  = R;                    // final, hg dead
  int* ip   = (int*)(R + 8388608);
  int* topi = ip;                     // 8192
  int* map  = ip + 8192;              // 8192
  int* rpos = ip + 16384;             // 8192
  int* cnts = ip + 24576;             // 4 sets * 24 ints

  dim3 blk(256);
  dim3 gN256(64, 4, 1);               // M=4096 tiles x N=256 tiles

  zero_ints<<<1, 128, 0, stream>>>(cnts, 96);
  pos_kernel<<<NHW, DM, 0, stream>>>(pos);
  tin_kernel<<<(NTOK*NCIN + 255)/256, blk, 0, stream>>>(x, tok);

  // src = tok @ Wi^T + bi
  gemm_k<false,false,true,false><<<dim3(64,4,1), blk, 0, stream>>>(
      tok, NCIN, Wi, NCIN, bi, src, DM, NTOK, DM, NCIN, nullptr, nullptr, nullptr, 0, 0);

  addpos_kernel<0><<<1024, blk, 0, stream>>>(src, pos, encp);
  addpos_kernel<1><<<1024, blk, 0, stream>>>(le, pos, tp);

  // self-attention MHA (layer-invariant: tgt re-broadcast each iter, enc fixed)
  gemm_k<false,false,true,false><<<gN256, blk, 0, stream>>>(
      tp, DM, Wqkv_s, DM, bqkv_s, q, DM, NTOK, DM, DM, nullptr, nullptr, nullptr, 0, 0);
  gemm_k<false,false,true,false><<<gN256, blk, 0, stream>>>(
      encp, DM, Wqkv_s + 256*DM, DM, bqkv_s + 256, k, DM, NTOK, DM, DM, nullptr, nullptr, nullptr, 0, 0);
  gemm_k<false,false,true,false><<<gN256, blk, 0, stream>>>(
      src, DM, Wqkv_s + 512*DM, DM, bqkv_s + 512, v, DM, NTOK, DM, DM, nullptr, nullptr, nullptr, 0, 0);
  attn_kernel<<<dim3(16,32), blk, 0, stream>>>(q, k, v, ao);
  gemm_k<false,false,true,false><<<gN256, blk, 0, stream>>>(
      ao, DM, Wo_s, DM, bo_s, t2s, DM, NTOK, DM, DM, nullptr, nullptr, nullptr, 0, 0);

  const float* decIn = src;
  for (int i = 0; i < 2; i++){
    add_ln_kernel<1><<<1024, blk, 0, stream>>>(le, t2s, ln_g + (4*i)*DM, ln_b + (4*i)*DM, tgtA);
    addpos_kernel<0><<<1024, blk, 0, stream>>>(tgtA, pos, tp);
    gemm_k<false,false,true,false><<<gN256, blk, 0, stream>>>(
        tp, DM, Wqkv_c, DM, bqkv_c, q, DM, NTOK, DM, DM, nullptr, nullptr, nullptr, 0, 0);
    addpos_kernel<0><<<1024, blk, 0, stream>>>(decIn, pos, decp);
    gemm_k<false,false,true,false><<<gN256, blk, 0, stream>>>(
        decp, DM, Wqkv_c + 256*DM, DM, bqkv_c + 256, k, DM, NTOK, DM, DM, nullptr, nullptr, nullptr, 0, 0);
    gemm_k<false,false,true,false><<<gN256, blk, 0, stream>>>(
        decIn, DM, Wqkv_c + 512*DM, DM, bqkv_c + 512, v, DM, NTOK, DM, DM, nullptr, nullptr, nullptr, 0, 0);
    attn_kernel<<<dim3(16,32), blk, 0, stream>>>(q, k, v, ao);
    gemm_k<false,false,true,false><<<gN256, blk, 0, stream>>>(
        ao, DM, Wo_c, DM, bo_c, v, DM, NTOK, DM, DM, nullptr, nullptr, nullptr, 0, 0);  // t2c -> v
    add_ln_kernel<0><<<1024, blk, 0, stream>>>(tgtA, v, ln_g + (4*i+1)*DM, ln_b + (4*i+1)*DM, od);

    // ---- MoE a ----
    {
      int* cnt  = cnts + (i*2)*24;
      int* cnt2 = cnt + 8;
      int* offs = cnt + 16;
      gate_kernel<<<1024, blk, 0, stream>>>(od, gw1, gb1, scores, topi, cnt);
      offs_kernel<<<1, 64, 0, stream>>>(cnt, offs, cnt2);
      assign_kernel<<<16, blk, 0, stream>>>(topi, offs, cnt2, map, rpos);
      gemm_k<true,true,false,true><<<dim3(64,16,8), blk, 0, stream>>>(
          od, DM, W1a, NDFF, b1a, hg, NDFF, 0, NDFF, DM, map, cnt, offs, (long)DM*NDFF, NDFF);
      gemm_k<true,false,false,false><<<dim3(64,4,8), blk, 0, stream>>>(
          hg, NDFF, W2a, DM, b2a, yg, DM, 0, DM, NDFF, nullptr, cnt, offs, (long)NDFF*DM, DM);
      moe_ln_kernel<<<1024, blk, 0, stream>>>(od, yg, scores, rpos,
          ln_g + (4*i+2)*DM, ln_b + (4*i+2)*DM, od2);
    }
    // ---- MoE b ----
    {
      int* cnt  = cnts + (i*2+1)*24;
      int* cnt2 = cnt + 8;
      int* offs = cnt + 16;
      gate_kernel<<<1024, blk, 0, stream>>>(od2, gw2, gb2, scores, topi, cnt);
      offs_kernel<<<1, 64, 0, stream>>>(cnt, offs, cnt2);
      assign_kernel<<<16, blk, 0, stream>>>(topi, offs, cnt2, map, rpos);
      gemm_k<true,true,false,true><<<dim3(64,16,8), blk, 0, stream>>>(
          od2, DM, W1b, NDFF, b1b, hg, NDFF, 0, NDFF, DM, map, cnt, offs, (long)DM*NDFF, NDFF);
      gemm_k<true,false,false,false><<<dim3(64,4,8), blk, 0, stream>>>(
          hg, NDFF, W2b, DM, b2b, yg, DM, 0, DM, NDFF, nullptr, cnt, offs, (long)NDFF*DM, DM);
      moe_ln_kernel<<<1024, blk, 0, stream>>>(od2, yg, scores, rpos,
          ln_g + (4*i+3)*DM, ln_b + (4*i+3)*DM, dec);
    }
    decIn = dec;
  }

  // rec = dec @ Wout^T + bout   [4096, 272]
  gemm_k<false,false,true,false><<<dim3(64,5,1), blk, 0, stream>>>(
      dec, DM, Wout, DM, bout, rec, NCIN, NTOK, NCIN, DM, nullptr, nullptr, nullptr, 0, 0);
  tout_kernel<<<(NTOK*NCIN + 255)/256, blk, 0, stream>>>(rec, (float*)d_out);
}

// Round 4
// 1782.225 us; speedup vs baseline: 1.3449x; 1.3449x over previous
//
#include <hip/hip_runtime.h>

#define NHW 1024
#define NB 4
#define DM 256
#define NTOK 4096      // NHW * NB
#define NCIN 272
#define NDFF 1024

typedef unsigned short u16;
typedef unsigned int u32;
typedef __attribute__((ext_vector_type(8))) short s16x8;
typedef __attribute__((ext_vector_type(4))) float f32x4;

__device__ __forceinline__ float4 ld4(const float* p){ return *(const float4*)p; }
__device__ __forceinline__ void st4(float* p, float4 v){ *(float4*)p = v; }

// split fp32 -> bf16 hi + bf16 lo  (hi = RNE(x); lo = RNE(x - hi), subtraction exact by Sterbenz)
__device__ __forceinline__ void splitf(float x, u16& h, u16& l){
  u32 u = __float_as_uint(x);
  u32 hu = (u + (0x7FFFu + ((u >> 16) & 1u))) >> 16;
  h = (u16)hu;
  float hf = __uint_as_float(hu << 16);
  float r = x - hf;
  u32 v = __float_as_uint(r);
  v += 0x7FFFu + ((v >> 16) & 1u);
  l = (u16)(v >> 16);
}

// ---------------- positional embedding ----------------
__global__ void pos_kernel(float* __restrict__ pos){
  int s = blockIdx.x, d = threadIdx.x;
  int row = s >> 5, col = s & 31;
  float base = (d < 128) ? (float)(row + 1) : (float)(col + 1);
  float val = base / (32.0f + 1e-6f) * 6.2831853071795864f;
  int dd = (d < 128) ? d : d - 128;
  int mf = dd >> 1;
  float f = powf(10000.0f, (float)mf * (1.0f/64.0f));
  float a = val / f;
  pos[s*DM + d] = (dd & 1) ? cosf(a) : sinf(a);
}

// ---------------- transposes ----------------
__global__ void tin_kernel(const float* __restrict__ x, float* __restrict__ tok){
  int idx = blockIdx.x*256 + threadIdx.x;
  if (idx >= NTOK*NCIN) return;
  int c = idx % NCIN;
  int n = idx / NCIN;
  int s = n >> 2, b = n & 3;
  tok[idx] = x[((long)(b*NCIN + c))*NHW + s];
}
__global__ void tout_kernel(const float* __restrict__ rec, float* __restrict__ out){
  int idx = blockIdx.x*256 + threadIdx.x;
  if (idx >= NTOK*NCIN) return;
  int s = idx & (NHW-1);
  int bc = idx >> 10;
  int b = bc / NCIN, c = bc % NCIN;
  out[idx] = rec[((long)(s*NB + b))*NCIN + c];
}

// ---------------- elementwise: out[n] = in[.] + pos[s] ----------------
template<int AMODE>   // 0: in indexed by n ; 1: in indexed by s (broadcast over batch)
__global__ __launch_bounds__(256) void addpos_kernel(const float* __restrict__ in,
    const float* __restrict__ pos, float* __restrict__ out){
  int gid = blockIdx.x*256 + threadIdx.x;
  int n = gid >> 6;
  int d4 = (gid & 63) << 2;
  int s = n >> 2;
  const float* ip = in + (AMODE ? (long)s*DM : (long)n*DM) + d4;
  float4 a = ld4(ip);
  float4 p = ld4(&pos[(long)s*DM + d4]);
  a.x += p.x; a.y += p.y; a.z += p.z; a.w += p.w;
  st4(&out[(long)n*DM + d4], a);
}

// -------- weight transpose+split: in [K][N] fp32 -> hi/lo planes [N][K] bf16 --------
__global__ __launch_bounds__(256) void tconv_kernel(const float* __restrict__ in,
    u16* __restrict__ oh, u16* __restrict__ ol, int K, int N){
  __shared__ float tile[32][33];
  long base = (long)blockIdx.z * (long)K * (long)N;
  int k0 = blockIdx.y*32, n0 = blockIdx.x*32;
  int tx = threadIdx.x & 31, ty = threadIdx.x >> 5;   // ty 0..7
  #pragma unroll
  for (int i=0;i<32;i+=8)
    tile[ty+i][tx] = in[base + (long)(k0+ty+i)*N + n0+tx];
  __syncthreads();
  #pragma unroll
  for (int i=0;i<32;i+=8){
    float v = tile[tx][ty+i];
    u16 h,l; splitf(v,h,l);
    long o = base + (long)(n0+ty+i)*K + k0+tx;
    oh[o]=h; ol[o]=l;
  }
}

// ---------------- split-bf16 MFMA GEMM: C = A @ B^T + bias (3-term) ----------------
// ASRC 0: A fp32 [M][lda], split during staging. ASRC 1: A packed hi|lo<<16 u32 [M][lda].
// BSRC 0: B fp32 [N][ldb] row-major, split during staging. BSRC 1: B pre-split planes Bh/Bl [N][ldb] u16.
// CDST 0: C fp32.  CDST 1: C packed u32 pairs.
// Tile 64x64, BK=32, 4 waves, each wave 32x32 via 2x2 mfma_16x16x32_bf16 frags.
template<bool GROUPED, bool INDIRECT, int ASRC, int BSRC, bool RELU, int CDST>
__global__ __launch_bounds__(256) void sgemm(
    const void* __restrict__ Av, int lda,
    const void* __restrict__ Bv, const void* __restrict__ Bv2, int ldb,
    const float* __restrict__ bias,
    void* __restrict__ Cv, int ldc,
    int M, int N, int K,
    const int* __restrict__ map,
    const int* __restrict__ cnt,
    const int* __restrict__ offs,
    long strideB, int strideBias)
{
  int e = GROUPED ? blockIdx.z : 0;
  int rows = GROUPED ? cnt[e] : M;
  int bm = blockIdx.x, bn = blockIdx.y;
  if (bm*64 >= rows) return;
  int row0 = GROUPED ? offs[e] : 0;
  const float* Af = (const float*)Av;
  const u32*   Ap = (const u32*)Av;
  const float* Bf = (const float*)Bv;
  const u16*   Bhp = (const u16*)Bv;
  const u16*   Blp = (const u16*)Bv2;
  if (GROUPED && BSRC==1){ Bhp += (long)e*strideB; Blp += (long)e*strideB; }
  const float* biasp = bias ? (GROUPED ? bias + (long)e*strideBias : bias) : nullptr;

  __shared__ u16 Ah[64*56], Al[64*56], Bh[64*56], Bl[64*56];  // 28 KB

  int tid = threadIdx.x;
  int sr = tid >> 2, sseg = tid & 3;     // staging: row 0..63, k-seg*8
  int w = tid >> 6, ln = tid & 63;
  int wm = w >> 1, wn = w & 1;
  int lr = ln & 15, lh = ln >> 4;

  int agrow = bm*64 + sr;
  bool aok = agrow < rows;
  long arow = 0;
  if (aok) arow = INDIRECT ? (long)map[row0 + agrow] : (long)(row0 + agrow);
  int bgrow = bn*64 + sr;
  bool bok = bgrow < N;

  const f32x4 z4 = {0.f,0.f,0.f,0.f};
  f32x4 acc00 = z4, acc01 = z4, acc10 = z4, acc11 = z4;
  const s16x8 z8 = {0,0,0,0,0,0,0,0};

  int soff = sr*56 + sseg*8;
  for (int k0 = 0; k0 < K; k0 += 32){
    int kk = k0 + sseg*8;
    bool kok = kk < K;        // K % 8 == 0 always
    s16x8 hv = z8, lv = z8;
    if (aok && kok){
      if (ASRC == 0){
        float4 x0 = ld4(&Af[arow*lda + kk]);
        float4 x1 = ld4(&Af[arow*lda + kk + 4]);
        float xs[8] = {x0.x,x0.y,x0.z,x0.w,x1.x,x1.y,x1.z,x1.w};
        #pragma unroll
        for (int t=0;t<8;t++){ u16 hh,ll; splitf(xs[t],hh,ll); hv[t]=(short)hh; lv[t]=(short)ll; }
      } else {
        uint4 p0 = *(const uint4*)&Ap[arow*lda + kk];
        uint4 p1 = *(const uint4*)&Ap[arow*lda + kk + 4];
        u32 ws[8] = {p0.x,p0.y,p0.z,p0.w,p1.x,p1.y,p1.z,p1.w};
        #pragma unroll
        for (int t=0;t<8;t++){ hv[t]=(short)(ws[t]&0xFFFFu); lv[t]=(short)(ws[t]>>16); }
      }
    }
    *(s16x8*)&Ah[soff] = hv; *(s16x8*)&Al[soff] = lv;
    hv = z8; lv = z8;
    if (bok && kok){
      if (BSRC == 0){
        float4 x0 = ld4(&Bf[(long)bgrow*ldb + kk]);
        float4 x1 = ld4(&Bf[(long)bgrow*ldb + kk + 4]);
        float xs[8] = {x0.x,x0.y,x0.z,x0.w,x1.x,x1.y,x1.z,x1.w};
        #pragma unroll
        for (int t=0;t<8;t++){ u16 hh,ll; splitf(xs[t],hh,ll); hv[t]=(short)hh; lv[t]=(short)ll; }
      } else {
        hv = *(const s16x8*)&Bhp[(long)bgrow*ldb + kk];
        lv = *(const s16x8*)&Blp[(long)bgrow*ldb + kk];
      }
    }
    *(s16x8*)&Bh[soff] = hv; *(s16x8*)&Bl[soff] = lv;
    __syncthreads();
    s16x8 a0h = *(const s16x8*)&Ah[(wm*32      + lr)*56 + lh*8];
    s16x8 a1h = *(const s16x8*)&Ah[(wm*32 + 16 + lr)*56 + lh*8];
    s16x8 a0l = *(const s16x8*)&Al[(wm*32      + lr)*56 + lh*8];
    s16x8 a1l = *(const s16x8*)&Al[(wm*32 + 16 + lr)*56 + lh*8];
    s16x8 b0h = *(const s16x8*)&Bh[(wn*32      + lr)*56 + lh*8];
    s16x8 b1h = *(const s16x8*)&Bh[(wn*32 + 16 + lr)*56 + lh*8];
    s16x8 b0l = *(const s16x8*)&Bl[(wn*32      + lr)*56 + lh*8];
    s16x8 b1l = *(const s16x8*)&Bl[(wn*32 + 16 + lr)*56 + lh*8];
    acc00 = __builtin_amdgcn_mfma_f32_16x16x32_bf16(a0h, b0h, acc00, 0,0,0);
    acc01 = __builtin_amdgcn_mfma_f32_16x16x32_bf16(a0h, b1h, acc01, 0,0,0);
    acc10 = __builtin_amdgcn_mfma_f32_16x16x32_bf16(a1h, b0h, acc10, 0,0,0);
    acc11 = __builtin_amdgcn_mfma_f32_16x16x32_bf16(a1h, b1h, acc11, 0,0,0);
    acc00 = __builtin_amdgcn_mfma_f32_16x16x32_bf16(a0h, b0l, acc00, 0,0,0);
    acc01 = __builtin_amdgcn_mfma_f32_16x16x32_bf16(a0h, b1l, acc01, 0,0,0);
    acc10 = __builtin_amdgcn_mfma_f32_16x16x32_bf16(a1h, b0l, acc10, 0,0,0);
    acc11 = __builtin_amdgcn_mfma_f32_16x16x32_bf16(a1h, b1l, acc11, 0,0,0);
    acc00 = __builtin_amdgcn_mfma_f32_16x16x32_bf16(a0l, b0h, acc00, 0,0,0);
    acc01 = __builtin_amdgcn_mfma_f32_16x16x32_bf16(a0l, b1h, acc01, 0,0,0);
    acc10 = __builtin_amdgcn_mfma_f32_16x16x32_bf16(a1l, b0h, acc10, 0,0,0);
    acc11 = __builtin_amdgcn_mfma_f32_16x16x32_bf16(a1l, b1h, acc11, 0,0,0);
    __syncthreads();
  }

  // epilogue: D row=(lane>>4)*4+reg, col=lane&15
  int c0 = bn*64 + wn*32 + lr;
  int c1 = c0 + 16;
  float bv0 = (biasp && c0 < N) ? biasp[c0] : 0.f;
  float bv1 = (biasp && c1 < N) ? biasp[c1] : 0.f;
  int rbase = bm*64 + wm*32 + lh*4;
  auto stc = [&](int gr, int gc, float vv){
    if (gr < rows && gc < N){
      float t = RELU ? fmaxf(vv, 0.f) : vv;
      if (CDST == 1){
        u16 h,l; splitf(t,h,l);
        ((u32*)Cv)[(long)(row0+gr)*ldc + gc] = (u32)h | ((u32)l << 16);
      } else {
        ((float*)Cv)[(long)(row0+gr)*ldc + gc] = t;
      }
    }
  };
  #pragma unroll
  for (int r = 0; r < 4; r++){
    stc(rbase + r,      c0, acc00[r] + bv0);
    stc(rbase + r,      c1, acc01[r] + bv1);
    stc(rbase + 16 + r, c0, acc10[r] + bv0);
    stc(rbase + 16 + r, c1, acc11[r] + bv1);
  }
}

// ---------------- flash attention, fp32, dh=32, S=T=1024 ----------------
__global__ __launch_bounds__(256) void attn_kernel(const float* __restrict__ Q,
    const float* __restrict__ Kb, const float* __restrict__ Vb, float* __restrict__ O)
{
  __shared__ float Ks[64][36];
  __shared__ float Vs[64][36];
  int qt = blockIdx.x, bh = blockIdx.y;
  int b = bh >> 3, h = bh & 7;
  int tid = threadIdx.x;
  int rl = tid >> 2, sub = tid & 3;
  int qpos = qt*64 + rl;
  long qrow = ((long)(qpos*NB + b))*DM + h*32;
  const float scale = 0.17677669529663687f;   // 1/sqrt(32)
  float q[32], o[32];
  float m = -1e30f, l = 0.f;
  #pragma unroll
  for (int d=0; d<32; d+=4){
    float4 t = ld4(&Q[qrow + d]);
    q[d]=t.x*scale; q[d+1]=t.y*scale; q[d+2]=t.z*scale; q[d+3]=t.w*scale;
    o[d]=0.f; o[d+1]=0.f; o[d+2]=0.f; o[d+3]=0.f;
  }
  for (int kt=0; kt<16; kt++){
    __syncthreads();
    #pragma unroll
    for (int i=0;i<2;i++){
      int fidx = tid*2 + i;
      int r = fidx >> 3, d4 = (fidx & 7) << 2;
      long g = ((long)((kt*64 + r)*NB + b))*DM + h*32 + d4;
      st4(&Ks[r][d4], ld4(&Kb[g]));
      st4(&Vs[r][d4], ld4(&Vb[g]));
    }
    __syncthreads();
    float s[16];
    #pragma unroll
    for (int j=0;j<16;j++){
      int c = (j<<2) + sub;
      float acc = 0.f;
      #pragma unroll
      for (int d=0; d<32; d+=4){
        float4 kv = ld4(&Ks[c][d]);
        acc += q[d]*kv.x + q[d+1]*kv.y + q[d+2]*kv.z + q[d+3]*kv.w;
      }
      s[j] = acc;
    }
    float tm = s[0];
    #pragma unroll
    for (int j=1;j<16;j++) tm = fmaxf(tm, s[j]);
    float M = fmaxf(m, tm);
    float alpha = __expf(m - M);
    l *= alpha;
    #pragma unroll
    for (int d=0; d<32; d++) o[d] *= alpha;
    #pragma unroll
    for (int j=0;j<16;j++){
      float p = __expf(s[j] - M);
      l += p;
      int c = (j<<2) + sub;
      #pragma unroll
      for (int d=0; d<32; d+=4){
        float4 vv = ld4(&Vs[c][d]);
        o[d]   += p*vv.x; o[d+1] += p*vv.y; o[d+2] += p*vv.z; o[d+3] += p*vv.w;
      }
    }
    m = M;
  }
  #pragma unroll
  for (int mask=1; mask<=2; mask<<=1){
    float m2 = __shfl_xor(m, mask);
    float l2 = __shfl_xor(l, mask);
    float M = fmaxf(m, m2);
    float a1 = __expf(m - M), a2 = __expf(m2 - M);
    l = a1*l + a2*l2;
    #pragma unroll
    for (int d=0; d<32; d++){
      float o2 = __shfl_xor(o[d], mask);
      o[d] = a1*o[d] + a2*o2;
    }
    m = M;
  }
  float inv = 1.f/l;
  float4 t0, t1;
  switch(sub){
    case 0: t0=make_float4(o[0],o[1],o[2],o[3]);     t1=make_float4(o[4],o[5],o[6],o[7]);     break;
    case 1: t0=make_float4(o[8],o[9],o[10],o[11]);   t1=make_float4(o[12],o[13],o[14],o[15]); break;
    case 2: t0=make_float4(o[16],o[17],o[18],o[19]); t1=make_float4(o[20],o[21],o[22],o[23]); break;
    default:t0=make_float4(o[24],o[25],o[26],o[27]); t1=make_float4(o[28],o[29],o[30],o[31]); break;
  }
  t0.x*=inv; t0.y*=inv; t0.z*=inv; t0.w*=inv;
  t1.x*=inv; t1.y*=inv; t1.z*=inv; t1.w*=inv;
  st4(&O[qrow + sub*8], t0);
  st4(&O[qrow + sub*8 + 4], t1);
}

// ---------------- fused add + LayerNorm (wave per row) ----------------
__device__ __forceinline__ float wave_sum(float v){
  #pragma unroll
  for (int m=1; m<64; m<<=1) v += __shfl_xor(v, m);
  return v;
}

template<int AMODE>
__global__ __launch_bounds__(256) void add_ln_kernel(const float* __restrict__ A,
    const float* __restrict__ Bv, const float* __restrict__ g, const float* __restrict__ beta,
    float* __restrict__ out)
{
  int row = blockIdx.x*4 + (threadIdx.x >> 6);
  int lane = threadIdx.x & 63;
  const float* ap = A + (AMODE ? (long)(row>>2)*DM : (long)row*DM);
  float4 a = ld4(&ap[lane*4]);
  float4 b = ld4(&Bv[(long)row*DM + lane*4]);
  a.x+=b.x; a.y+=b.y; a.z+=b.z; a.w+=b.w;
  float sum = wave_sum(a.x+a.y+a.z+a.w);
  float sq  = wave_sum(a.x*a.x + a.y*a.y + a.z*a.z + a.w*a.w);
  float mean = sum * (1.f/DM);
  float var  = sq * (1.f/DM) - mean*mean;
  float inv = 1.0f / sqrtf(var + 1e-5f);
  float4 gg = ld4(&g[lane*4]);
  float4 bb = ld4(&beta[lane*4]);
  float4 ov;
  ov.x = (a.x-mean)*inv*gg.x + bb.x;
  ov.y = (a.y-mean)*inv*gg.y + bb.y;
  ov.z = (a.z-mean)*inv*gg.z + bb.z;
  ov.w = (a.w-mean)*inv*gg.w + bb.w;
  st4(&out[(long)row*DM + lane*4], ov);
}

__global__ __launch_bounds__(256) void moe_ln_kernel(const float* __restrict__ base,
    const float* __restrict__ yg, const float* __restrict__ scores, const int* __restrict__ rpos,
    const float* __restrict__ g, const float* __restrict__ beta, float* __restrict__ out)
{
  int row = blockIdx.x*4 + (threadIdx.x >> 6);
  int lane = threadIdx.x & 63;
  float s0 = scores[row*2], s1 = scores[row*2+1];
  int r0 = rpos[row*2], r1 = rpos[row*2+1];
  float4 a  = ld4(&base[(long)row*DM + lane*4]);
  float4 y0 = ld4(&yg[(long)r0*DM + lane*4]);
  float4 y1 = ld4(&yg[(long)r1*DM + lane*4]);
  a.x += s0*y0.x + s1*y1.x;
  a.y += s0*y0.y + s1*y1.y;
  a.z += s0*y0.z + s1*y1.z;
  a.w += s0*y0.w + s1*y1.w;
  float sum = wave_sum(a.x+a.y+a.z+a.w);
  float sq  = wave_sum(a.x*a.x + a.y*a.y + a.z*a.z + a.w*a.w);
  float mean = sum * (1.f/DM);
  float var  = sq * (1.f/DM) - mean*mean;
  float inv = 1.0f / sqrtf(var + 1e-5f);
  float4 gg = ld4(&g[lane*4]);
  float4 bb = ld4(&beta[lane*4]);
  float4 ov;
  ov.x = (a.x-mean)*inv*gg.x + bb.x;
  ov.y = (a.y-mean)*inv*gg.y + bb.y;
  ov.z = (a.z-mean)*inv*gg.z + bb.z;
  ov.w = (a.w-mean)*inv*gg.w + bb.w;
  st4(&out[(long)row*DM + lane*4], ov);
}

// ---------------- MoE gate ----------------
__global__ __launch_bounds__(256) void gate_kernel(const float* __restrict__ X,
    const float* __restrict__ GW, const float* __restrict__ GB,
    float* __restrict__ scores, int* __restrict__ topi, int* __restrict__ cnt)
{
  int row = blockIdx.x*4 + (threadIdx.x >> 6);
  int lane = threadIdx.x & 63;
  float4 x = ld4(&X[(long)row*DM + lane*4]);
  float lg[8];
  #pragma unroll
  for (int e=0; e<8; e++){
    float4 wv = ld4(&GW[e*DM + lane*4]);
    lg[e] = x.x*wv.x + x.y*wv.y + x.z*wv.z + x.w*wv.w;
  }
  #pragma unroll
  for (int mask=1; mask<64; mask<<=1){
    #pragma unroll
    for (int e=0; e<8; e++) lg[e] += __shfl_xor(lg[e], mask);
  }
  #pragma unroll
  for (int e=0; e<8; e++) lg[e] += GB[e];
  int i0 = 0; float v0 = lg[0];
  #pragma unroll
  for (int e=1; e<8; e++) if (lg[e] > v0){ v0 = lg[e]; i0 = e; }
  int i1 = -1; float v1 = -1e30f;
  #pragma unroll
  for (int e=0; e<8; e++) if (e != i0 && lg[e] > v1){ v1 = lg[e]; i1 = e; }
  if (lane == 0){
    float ee = expf(v1 - v0);
    float inv = 1.f/(1.f + ee);
    scores[row*2]   = inv;
    scores[row*2+1] = ee*inv;
    topi[row*2]   = i0;
    topi[row*2+1] = i1;
    atomicAdd(&cnt[i0], 1);
    atomicAdd(&cnt[i1], 1);
  }
}

__global__ void offs_kernel(const int* __restrict__ cnt, int* __restrict__ offs,
                            int* __restrict__ cnt2){
  if (threadIdx.x == 0){
    int o = 0;
    for (int e=0; e<8; e++){ offs[e] = o; o += cnt[e]; cnt2[e] = 0; }
  }
}

__global__ void assign_kernel(const int* __restrict__ topi, const int* __restrict__ offs,
    int* __restrict__ cnt2, int* __restrict__ map, int* __restrict__ rpos)
{
  int n = blockIdx.x*256 + threadIdx.x;
  if (n >= NTOK) return;
  for (int j=0; j<2; j++){
    int e = topi[n*2+j];
    int slot = atomicAdd(&cnt2[e], 1);
    int r = offs[e] + slot;
    map[r] = n;
    rpos[n*2+j] = r;
  }
}

__global__ void zero_ints(int* p, int n){
  int i = blockIdx.x*256 + threadIdx.x;
  if (i < n) p[i] = 0;
}

// =================================================================
extern "C" void kernel_launch(void* const* d_in, const int* in_sizes, int n_in,
                              void* d_out, int out_size, void* d_ws, size_t ws_size,
                              hipStream_t stream)
{
  const float* x      = (const float*)d_in[0];
  const float* Wi     = (const float*)d_in[1];
  const float* bi     = (const float*)d_in[2];
  const float* le     = (const float*)d_in[3];
  const float* Wqkv_s = (const float*)d_in[4];
  const float* bqkv_s = (const float*)d_in[5];
  const float* Wo_s   = (const float*)d_in[6];
  const float* bo_s   = (const float*)d_in[7];
  const float* Wqkv_c = (const float*)d_in[8];
  const float* bqkv_c = (const float*)d_in[9];
  const float* Wo_c   = (const float*)d_in[10];
  const float* bo_c   = (const float*)d_in[11];
  const float* ln_g   = (const float*)d_in[12];
  const float* ln_b   = (const float*)d_in[13];
  const float* gw1    = (const float*)d_in[14];
  const float* gb1    = (const float*)d_in[15];
  const float* W1a    = (const float*)d_in[16];
  const float* b1a    = (const float*)d_in[17];
  const float* W2a    = (const float*)d_in[18];
  const float* b2a    = (const float*)d_in[19];
  const float* gw2    = (const float*)d_in[20];
  const float* gb2    = (const float*)d_in[21];
  const float* W1b    = (const float*)d_in[22];
  const float* b1b    = (const float*)d_in[23];
  const float* W2b    = (const float*)d_in[24];
  const float* b2b    = (const float*)d_in[25];
  const float* Wout   = (const float*)d_in[26];
  const float* bout   = (const float*)d_in[27];

  float* w = (float*)d_ws;
  const long SZ = 1048576;            // NTOK*DM
  float* pos  = w;                    // 262144
  float* src  = pos  + 262144;
  float* t2s  = src  + SZ;
  float* tgtA = t2s  + SZ;
  float* dec  = tgtA + SZ;
  float* od   = dec  + SZ;
  float* od2  = od   + SZ;
  float* yg   = od2  + SZ;            // 2,097,152 fp32
  float* scores = yg + 2097152;       // 8192
  // pre-split MoE weights: 8 planes x 2,097,152 u16 (hi/lo per tensor)
  u16* wsp  = (u16*)(scores + 8192);
  u16* W1ah = wsp;             u16* W1al = wsp + 2097152;
  u16* W1bh = wsp + 4194304;   u16* W1bl = wsp + 6291456;
  u16* W2ah = wsp + 8388608;   u16* W2al = wsp + 10485760;
  u16* W2bh = wsp + 12582912;  u16* W2bl = wsp + 14680064;
  // overlay region R: 8,388,608 floats
  float* R   = scores + 8192 + 8388608;
  float* tok = R;                     // [NTOK*NCIN], dead before encp written
  float* encp= R;
  float* tp  = R + SZ;
  float* decp= R + 2*SZ;
  float* q   = R + 3*SZ;
  float* k   = R + 4*SZ;
  float* v   = R + 5*SZ;              // also reused as t2c
  float* ao  = R + 6*SZ;
  u32*  hg   = (u32*)R;               // 8192*1024 packed pairs (MoE phase; q..ao dead)
  float* rec = R;                     // final (hg dead)
  int* ip   = (int*)(R + 8388608);
  int* topi = ip;                     // 8192
  int* map  = ip + 8192;              // 8192
  int* rpos = ip + 16384;             // 8192
  int* cnts = ip + 24576;             // 4 sets * 24 ints

  dim3 blk(256);
  dim3 gN256(64, 4, 1);

  zero_ints<<<1, 128, 0, stream>>>(cnts, 96);
  pos_kernel<<<NHW, DM, 0, stream>>>(pos);
  tin_kernel<<<(NTOK*NCIN + 255)/256, blk, 0, stream>>>(x, tok);

  // one-time MoE weight transpose+split
  tconv_kernel<<<dim3(32, 8, 8), blk, 0, stream>>>(W1a, W1ah, W1al, DM,   NDFF);
  tconv_kernel<<<dim3(32, 8, 8), blk, 0, stream>>>(W1b, W1bh, W1bl, DM,   NDFF);
  tconv_kernel<<<dim3(8, 32, 8), blk, 0, stream>>>(W2a, W2ah, W2al, NDFF, DM);
  tconv_kernel<<<dim3(8, 32, 8), blk, 0, stream>>>(W2b, W2bh, W2bl, NDFF, DM);

  // src = tok @ Wi^T + bi   (K=272)
  sgemm<false,false,0,0,false,0><<<dim3(64,4,1), blk, 0, stream>>>(
      tok, NCIN, Wi, nullptr, NCIN, bi, src, DM, NTOK, DM, NCIN, nullptr, nullptr, nullptr, 0, 0);

  addpos_kernel<0><<<1024, blk, 0, stream>>>(src, pos, encp);
  addpos_kernel<1><<<1024, blk, 0, stream>>>(le, pos, tp);

  // self-attention MHA (layer-invariant, hoisted out of the loop)
  sgemm<false,false,0,0,false,0><<<gN256, blk, 0, stream>>>(
      tp, DM, Wqkv_s, nullptr, DM, bqkv_s, q, DM, NTOK, DM, DM, nullptr, nullptr, nullptr, 0, 0);
  sgemm<false,false,0,0,false,0><<<gN256, blk, 0, stream>>>(
      encp, DM, Wqkv_s + 256*DM, nullptr, DM, bqkv_s + 256, k, DM, NTOK, DM, DM, nullptr, nullptr, nullptr, 0, 0);
  sgemm<false,false,0,0,false,0><<<gN256, blk, 0, stream>>>(
      src, DM, Wqkv_s + 512*DM, nullptr, DM, bqkv_s + 512, v, DM, NTOK, DM, DM, nullptr, nullptr, nullptr, 0, 0);
  attn_kernel<<<dim3(16,32), blk, 0, stream>>>(q, k, v, ao);
  sgemm<false,false,0,0,false,0><<<gN256, blk, 0, stream>>>(
      ao, DM, Wo_s, nullptr, DM, bo_s, t2s, DM, NTOK, DM, DM, nullptr, nullptr, nullptr, 0, 0);

  const float* decIn = src;
  for (int i = 0; i < 2; i++){
    add_ln_kernel<1><<<1024, blk, 0, stream>>>(le, t2s, ln_g + (4*i)*DM, ln_b + (4*i)*DM, tgtA);
    addpos_kernel<0><<<1024, blk, 0, stream>>>(tgtA, pos, tp);
    sgemm<false,false,0,0,false,0><<<gN256, blk, 0, stream>>>(
        tp, DM, Wqkv_c, nullptr, DM, bqkv_c, q, DM, NTOK, DM, DM, nullptr, nullptr, nullptr, 0, 0);
    addpos_kernel<0><<<1024, blk, 0, stream>>>(decIn, pos, decp);
    sgemm<false,false,0,0,false,0><<<gN256, blk, 0, stream>>>(
        decp, DM, Wqkv_c + 256*DM, nullptr, DM, bqkv_c + 256, k, DM, NTOK, DM, DM, nullptr, nullptr, nullptr, 0, 0);
    sgemm<false,false,0,0,false,0><<<gN256, blk, 0, stream>>>(
        decIn, DM, Wqkv_c + 512*DM, nullptr, DM, bqkv_c + 512, v, DM, NTOK, DM, DM, nullptr, nullptr, nullptr, 0, 0);
    attn_kernel<<<dim3(16,32), blk, 0, stream>>>(q, k, v, ao);
    sgemm<false,false,0,0,false,0><<<gN256, blk, 0, stream>>>(
        ao, DM, Wo_c, nullptr, DM, bo_c, v, DM, NTOK, DM, DM, nullptr, nullptr, nullptr, 0, 0);  // t2c -> v
    add_ln_kernel<0><<<1024, blk, 0, stream>>>(tgtA, v, ln_g + (4*i+1)*DM, ln_b + (4*i+1)*DM, od);

    // ---- MoE a ----
    {
      int* cnt  = cnts + (i*2)*24;
      int* cnt2 = cnt + 8;
      int* offs = cnt + 16;
      gate_kernel<<<1024, blk, 0, stream>>>(od, gw1, gb1, scores, topi, cnt);
      offs_kernel<<<1, 64, 0, stream>>>(cnt, offs, cnt2);
      assign_kernel<<<16, blk, 0, stream>>>(topi, offs, cnt2, map, rpos);
      sgemm<true,true,0,1,true,1><<<dim3(64,16,8), blk, 0, stream>>>(
          od, DM, W1ah, W1al, DM, b1a, hg, NDFF, 0, NDFF, DM, map, cnt, offs, 262144L, NDFF);
      sgemm<true,false,1,1,false,0><<<dim3(64,4,8), blk, 0, stream>>>(
          hg, NDFF, W2ah, W2al, NDFF, b2a, yg, DM, 0, DM, NDFF, nullptr, cnt, offs, 262144L, DM);
      moe_ln_kernel<<<1024, blk, 0, stream>>>(od, yg, scores, rpos,
          ln_g + (4*i+2)*DM, ln_b + (4*i+2)*DM, od2);
    }
    // ---- MoE b ----
    {
      int* cnt  = cnts + (i*2+1)*24;
      int* cnt2 = cnt + 8;
      int* offs = cnt + 16;
      gate_kernel<<<1024, blk, 0, stream>>>(od2, gw2, gb2, scores, topi, cnt);
      offs_kernel<<<1, 64, 0, stream>>>(cnt, offs, cnt2);
      assign_kernel<<<16, blk, 0, stream>>>(topi, offs, cnt2, map, rpos);
      sgemm<true,true,0,1,true,1><<<dim3(64,16,8), blk, 0, stream>>>(
          od2, DM, W1bh, W1bl, DM, b1b, hg, NDFF, 0, NDFF, DM, map, cnt, offs, 262144L, NDFF);
      sgemm<true,false,1,1,false,0><<<dim3(64,4,8), blk, 0, stream>>>(
          hg, NDFF, W2bh, W2bl, NDFF, b2b, yg, DM, 0, DM, NDFF, nullptr, cnt, offs, 262144L, DM);
      moe_ln_kernel<<<1024, blk, 0, stream>>>(od2, yg, scores, rpos,
          ln_g + (4*i+3)*DM, ln_b + (4*i+3)*DM, dec);
    }
    decIn = dec;
  }

  // rec = dec @ Wout^T + bout   [4096, 272]
  sgemm<false,false,0,0,false,0><<<dim3(64,5,1), blk, 0, stream>>>(
      dec, DM, Wout, nullptr, DM, bout, rec, NCIN, NTOK, NCIN, DM, nullptr, nullptr, nullptr, 0, 0);
  tout_kernel<<<(NTOK*NCIN + 255)/256, blk, 0, stream>>>(rec, (float*)d_out);
}

// Round 5
// 1668.722 us; speedup vs baseline: 1.4364x; 1.0680x over previous
//
#include <hip/hip_runtime.h>

#define NHW 1024
#define NB 4
#define DM 256
#define NTOK 4096      // NHW * NB
#define NCIN 272
#define NDFF 1024

typedef unsigned short u16;
typedef unsigned int u32;
typedef __attribute__((ext_vector_type(8))) short s16x8;
typedef __attribute__((ext_vector_type(4))) float f32x4;

__device__ __forceinline__ float4 ld4(const float* p){ return *(const float4*)p; }
__device__ __forceinline__ void st4(float* p, float4 v){ *(float4*)p = v; }

// split fp32 -> bf16 hi + bf16 lo  (hi = RNE(x); lo = RNE(x - hi))
__device__ __forceinline__ void splitf(float x, u16& h, u16& l){
  u32 u = __float_as_uint(x);
  u32 hu = (u + (0x7FFFu + ((u >> 16) & 1u))) >> 16;
  h = (u16)hu;
  float hf = __uint_as_float(hu << 16);
  float r = x - hf;
  u32 v = __float_as_uint(r);
  v += 0x7FFFu + ((v >> 16) & 1u);
  l = (u16)(v >> 16);
}

// ---------------- positional embedding ----------------
__global__ void pos_kernel(float* __restrict__ pos){
  int s = blockIdx.x, d = threadIdx.x;
  int row = s >> 5, col = s & 31;
  float base = (d < 128) ? (float)(row + 1) : (float)(col + 1);
  float val = base / (32.0f + 1e-6f) * 6.2831853071795864f;
  int dd = (d < 128) ? d : d - 128;
  int mf = dd >> 1;
  float f = powf(10000.0f, (float)mf * (1.0f/64.0f));
  float a = val / f;
  pos[s*DM + d] = (dd & 1) ? cosf(a) : sinf(a);
}

// ---------------- transposes ----------------
__global__ void tin_kernel(const float* __restrict__ x, float* __restrict__ tok){
  int idx = blockIdx.x*256 + threadIdx.x;
  if (idx >= NTOK*NCIN) return;
  int c = idx % NCIN;
  int n = idx / NCIN;
  int s = n >> 2, b = n & 3;
  tok[idx] = x[((long)(b*NCIN + c))*NHW + s];
}
__global__ void tout_kernel(const float* __restrict__ rec, float* __restrict__ out){
  int idx = blockIdx.x*256 + threadIdx.x;
  if (idx >= NTOK*NCIN) return;
  int s = idx & (NHW-1);
  int bc = idx >> 10;
  int b = bc / NCIN, c = bc % NCIN;
  out[idx] = rec[((long)(s*NB + b))*NCIN + c];
}

// ---------------- elementwise: out[n] = in[.] + pos[s] ----------------
template<int AMODE>   // 0: in indexed by n ; 1: in indexed by s (broadcast over batch)
__global__ __launch_bounds__(256) void addpos_kernel(const float* __restrict__ in,
    const float* __restrict__ pos, float* __restrict__ out){
  int gid = blockIdx.x*256 + threadIdx.x;
  int n = gid >> 6;
  int d4 = (gid & 63) << 2;
  int s = n >> 2;
  const float* ip = in + (AMODE ? (long)s*DM : (long)n*DM) + d4;
  float4 a = ld4(ip);
  float4 p = ld4(&pos[(long)s*DM + d4]);
  a.x += p.x; a.y += p.y; a.z += p.z; a.w += p.w;
  st4(&out[(long)n*DM + d4], a);
}

// -------- weight transpose+split: in [K][N] fp32 -> hi/lo planes [N][K] bf16 --------
__global__ __launch_bounds__(256) void tconv_kernel(const float* __restrict__ in,
    u16* __restrict__ oh, u16* __restrict__ ol, int K, int N){
  __shared__ float tile[32][33];
  long base = (long)blockIdx.z * (long)K * (long)N;
  int k0 = blockIdx.y*32, n0 = blockIdx.x*32;
  int tx = threadIdx.x & 31, ty = threadIdx.x >> 5;   // ty 0..7
  #pragma unroll
  for (int i=0;i<32;i+=8)
    tile[ty+i][tx] = in[base + (long)(k0+ty+i)*N + n0+tx];
  __syncthreads();
  #pragma unroll
  for (int i=0;i<32;i+=8){
    float v = tile[tx][ty+i];
    u16 h,l; splitf(v,h,l);
    long o = base + (long)(n0+ty+i)*K + k0+tx;
    oh[o]=h; ol[o]=l;
  }
}

// ---------------- split-bf16 MFMA GEMM: C = A @ B^T + bias (3-term) ----------------
// Tile 32x64, BK=32, 256 threads = 4 waves; wave computes 16x32 (2 frags x 3 terms).
// ASRC 0: A fp32, split on stage. ASRC 1: A packed hi|lo<<16 u32.
// BSRC 0: B fp32 [N][ldb]. BSRC 1: B pre-split planes u16.
// CDST 0: fp32. CDST 1: packed u32 pairs.
// BATCH: blockIdx.z in {0,1,2} selects A0/A1/A2 -> C0/C1/C2, B row-offset z*256.
template<bool GROUPED, bool INDIRECT, int ASRC, int BSRC, bool RELU, int CDST, bool BATCH>
__global__ __launch_bounds__(256) void sgemm(
    const void* __restrict__ Av, const void* __restrict__ Av1, const void* __restrict__ Av2, int lda,
    const void* __restrict__ Bv, const void* __restrict__ Bv2, int ldb,
    const float* __restrict__ bias,
    void* __restrict__ Cv, void* __restrict__ Cv1, void* __restrict__ Cv2, int ldc,
    int M, int N, int K,
    const int* __restrict__ map,
    const int* __restrict__ cnt,
    const int* __restrict__ offs,
    long strideB, int strideBias)
{
  int e = GROUPED ? blockIdx.z : 0;
  int z = BATCH ? blockIdx.z : 0;
  int rows = GROUPED ? cnt[e] : M;
  int bm = blockIdx.x, bn = blockIdx.y;
  if (bm*32 >= rows) return;
  int row0 = GROUPED ? offs[e] : 0;
  const float* Af = (const float*)(BATCH ? (z==0?Av:(z==1?Av1:Av2)) : Av);
  const u32*   Ap = (const u32*)Av;
  const float* Bf = (const float*)Bv;
  const u16*   Bhp = (const u16*)Bv;
  const u16*   Blp = (const u16*)Bv2;
  if (GROUPED && BSRC==1){ Bhp += (long)e*strideB; Blp += (long)e*strideB; }
  int bofs = BATCH ? z*256 : 0;
  const float* biasp = bias ? (GROUPED ? bias + (long)e*strideBias : bias + bofs) : nullptr;
  void* Cp = BATCH ? (z==0?Cv:(z==1?Cv1:Cv2)) : Cv;

  __shared__ u16 Ah[32*56], Al[32*56], Bh[64*56], Bl[64*56];  // 21 KB

  int tid = threadIdx.x;
  int w = tid >> 6, ln = tid & 63;
  int wm = w >> 1, wn = w & 1;
  int lr = ln & 15, lh = ln >> 4;
  int srow = tid >> 2, sseg = tid & 3;

  int bgrow = bn*64 + srow;              // B tile row (0..63)
  bool bok = bgrow < N;
  int agrow = bm*32 + srow;              // A tile row, valid for tid<128
  bool aok = (tid < 128) && (agrow < rows);
  long arow = 0;
  if (aok) arow = INDIRECT ? (long)map[row0 + agrow] : (long)(row0 + agrow);

  const f32x4 z4 = {0.f,0.f,0.f,0.f};
  f32x4 acc0 = z4, acc1 = z4;
  const s16x8 z8 = {0,0,0,0,0,0,0,0};

  for (int k0 = 0; k0 < K; k0 += 32){
    int kk = k0 + sseg*8;
    bool kok = kk < K;                   // K % 8 == 0 always
    // ---- stage B (all 256 threads) ----
    s16x8 hv = z8, lv = z8;
    if (bok && kok){
      if (BSRC == 0){
        float4 x0 = ld4(&Bf[(long)(bgrow+bofs)*ldb + kk]);
        float4 x1 = ld4(&Bf[(long)(bgrow+bofs)*ldb + kk + 4]);
        float xs[8] = {x0.x,x0.y,x0.z,x0.w,x1.x,x1.y,x1.z,x1.w};
        #pragma unroll
        for (int t=0;t<8;t++){ u16 hh,ll; splitf(xs[t],hh,ll); hv[t]=(short)hh; lv[t]=(short)ll; }
      } else {
        hv = *(const s16x8*)&Bhp[(long)bgrow*ldb + kk];
        lv = *(const s16x8*)&Blp[(long)bgrow*ldb + kk];
      }
    }
    *(s16x8*)&Bh[srow*56 + sseg*8] = hv;
    *(s16x8*)&Bl[srow*56 + sseg*8] = lv;
    // ---- stage A (threads 0..127) ----
    if (tid < 128){
      hv = z8; lv = z8;
      if (aok && kok){
        if (ASRC == 0){
          float4 x0 = ld4(&Af[arow*lda + kk]);
          float4 x1 = ld4(&Af[arow*lda + kk + 4]);
          float xs[8] = {x0.x,x0.y,x0.z,x0.w,x1.x,x1.y,x1.z,x1.w};
          #pragma unroll
          for (int t=0;t<8;t++){ u16 hh,ll; splitf(xs[t],hh,ll); hv[t]=(short)hh; lv[t]=(short)ll; }
        } else {
          uint4 p0 = *(const uint4*)&Ap[arow*lda + kk];
          uint4 p1 = *(const uint4*)&Ap[arow*lda + kk + 4];
          u32 ws[8] = {p0.x,p0.y,p0.z,p0.w,p1.x,p1.y,p1.z,p1.w};
          #pragma unroll
          for (int t=0;t<8;t++){ hv[t]=(short)(ws[t]&0xFFFFu); lv[t]=(short)(ws[t]>>16); }
        }
      }
      *(s16x8*)&Ah[srow*56 + sseg*8] = hv;
      *(s16x8*)&Al[srow*56 + sseg*8] = lv;
    }
    __syncthreads();
    s16x8 a0h = *(const s16x8*)&Ah[(wm*16 + lr)*56 + lh*8];
    s16x8 a0l = *(const s16x8*)&Al[(wm*16 + lr)*56 + lh*8];
    s16x8 b0h = *(const s16x8*)&Bh[(wn*32      + lr)*56 + lh*8];
    s16x8 b1h = *(const s16x8*)&Bh[(wn*32 + 16 + lr)*56 + lh*8];
    s16x8 b0l = *(const s16x8*)&Bl[(wn*32      + lr)*56 + lh*8];
    s16x8 b1l = *(const s16x8*)&Bl[(wn*32 + 16 + lr)*56 + lh*8];
    acc0 = __builtin_amdgcn_mfma_f32_16x16x32_bf16(a0h, b0h, acc0, 0,0,0);
    acc1 = __builtin_amdgcn_mfma_f32_16x16x32_bf16(a0h, b1h, acc1, 0,0,0);
    acc0 = __builtin_amdgcn_mfma_f32_16x16x32_bf16(a0h, b0l, acc0, 0,0,0);
    acc1 = __builtin_amdgcn_mfma_f32_16x16x32_bf16(a0h, b1l, acc1, 0,0,0);
    acc0 = __builtin_amdgcn_mfma_f32_16x16x32_bf16(a0l, b0h, acc0, 0,0,0);
    acc1 = __builtin_amdgcn_mfma_f32_16x16x32_bf16(a0l, b1h, acc1, 0,0,0);
    __syncthreads();
  }

  // epilogue: D row=(lane>>4)*4+reg, col=lane&15
  int c0 = bn*64 + wn*32 + lr;
  int c1 = c0 + 16;
  float bv0 = (biasp && c0 < N) ? biasp[c0] : 0.f;
  float bv1 = (biasp && c1 < N) ? biasp[c1] : 0.f;
  int rbase = bm*32 + wm*16 + lh*4;
  auto stc = [&](int gr, int gc, float vv){
    if (gr < rows && gc < N){
      float t = RELU ? fmaxf(vv, 0.f) : vv;
      if (CDST == 1){
        u16 h,l; splitf(t,h,l);
        ((u32*)Cp)[(long)(row0+gr)*ldc + gc] = (u32)h | ((u32)l << 16);
      } else {
        ((float*)Cp)[(long)(row0+gr)*ldc + gc] = t;
      }
    }
  };
  #pragma unroll
  for (int r = 0; r < 4; r++){
    stc(rbase + r, c0, acc0[r] + bv0);
    stc(rbase + r, c1, acc1[r] + bv1);
  }
}

// ---------------- flash attention, fp32, dh=32, S=T=1024 ----------------
// grid (32 qtiles, 32 bh); block 256 = 32 q-rows x 8 lanes/row.
__global__ __launch_bounds__(256) void attn_kernel(const float* __restrict__ Q,
    const float* __restrict__ Kb, const float* __restrict__ Vb, float* __restrict__ O)
{
  __shared__ float Ks[64][36];
  __shared__ float Vs[64][36];
  int qt = blockIdx.x, bh = blockIdx.y;
  int b = bh >> 3, h = bh & 7;
  int tid = threadIdx.x;
  int rl = tid >> 3, sub = tid & 7;
  int qpos = qt*32 + rl;
  long qrow = ((long)(qpos*NB + b))*DM + h*32;
  const float scale = 0.17677669529663687f;   // 1/sqrt(32)
  float q[32], o[32];
  float m = -1e30f, l = 0.f;
  #pragma unroll
  for (int d=0; d<32; d+=4){
    float4 t = ld4(&Q[qrow + d]);
    q[d]=t.x*scale; q[d+1]=t.y*scale; q[d+2]=t.z*scale; q[d+3]=t.w*scale;
    o[d]=0.f; o[d+1]=0.f; o[d+2]=0.f; o[d+3]=0.f;
  }
  for (int kt=0; kt<16; kt++){
    __syncthreads();
    #pragma unroll
    for (int i=0;i<2;i++){
      int fidx = tid*2 + i;
      int r = fidx >> 3, d4 = (fidx & 7) << 2;
      long g = ((long)((kt*64 + r)*NB + b))*DM + h*32 + d4;
      st4(&Ks[r][d4], ld4(&Kb[g]));
      st4(&Vs[r][d4], ld4(&Vb[g]));
    }
    __syncthreads();
    float s[8];
    #pragma unroll
    for (int j=0;j<8;j++){
      int c = (j<<3) + sub;               // 8 subs -> distinct bank quads; rows broadcast
      float acc = 0.f;
      #pragma unroll
      for (int d=0; d<32; d+=4){
        float4 kv = ld4(&Ks[c][d]);
        acc += q[d]*kv.x + q[d+1]*kv.y + q[d+2]*kv.z + q[d+3]*kv.w;
      }
      s[j] = acc;
    }
    float tm = s[0];
    #pragma unroll
    for (int j=1;j<8;j++) tm = fmaxf(tm, s[j]);
    float M = fmaxf(m, tm);
    float alpha = __expf(m - M);
    l *= alpha;
    #pragma unroll
    for (int d=0; d<32; d++) o[d] *= alpha;
    #pragma unroll
    for (int j=0;j<8;j++){
      float p = __expf(s[j] - M);
      l += p;
      int c = (j<<3) + sub;
      #pragma unroll
      for (int d=0; d<32; d+=4){
        float4 vv = ld4(&Vs[c][d]);
        o[d]   += p*vv.x; o[d+1] += p*vv.y; o[d+2] += p*vv.z; o[d+3] += p*vv.w;
      }
    }
    m = M;
  }
  // merge the 8 partial states (key-range split) across lanes sub=0..7
  #pragma unroll
  for (int mask=1; mask<=4; mask<<=1){
    float m2 = __shfl_xor(m, mask);
    float l2 = __shfl_xor(l, mask);
    float M = fmaxf(m, m2);
    float a1 = __expf(m - M), a2 = __expf(m2 - M);
    l = a1*l + a2*l2;
    #pragma unroll
    for (int d=0; d<32; d++){
      float o2 = __shfl_xor(o[d], mask);
      o[d] = a1*o[d] + a2*o2;
    }
    m = M;
  }
  float inv = 1.f/l;
  float4 t0;
  switch(sub){
    case 0: t0=make_float4(o[0],o[1],o[2],o[3]);     break;
    case 1: t0=make_float4(o[4],o[5],o[6],o[7]);     break;
    case 2: t0=make_float4(o[8],o[9],o[10],o[11]);   break;
    case 3: t0=make_float4(o[12],o[13],o[14],o[15]); break;
    case 4: t0=make_float4(o[16],o[17],o[18],o[19]); break;
    case 5: t0=make_float4(o[20],o[21],o[22],o[23]); break;
    case 6: t0=make_float4(o[24],o[25],o[26],o[27]); break;
    default:t0=make_float4(o[28],o[29],o[30],o[31]); break;
  }
  t0.x*=inv; t0.y*=inv; t0.z*=inv; t0.w*=inv;
  st4(&O[qrow + sub*4], t0);
}

// ---------------- fused add + LayerNorm (wave per row) ----------------
__device__ __forceinline__ float wave_sum(float v){
  #pragma unroll
  for (int m=1; m<64; m<<=1) v += __shfl_xor(v, m);
  return v;
}

template<int AMODE>
__global__ __launch_bounds__(256) void add_ln_kernel(const float* __restrict__ A,
    const float* __restrict__ Bv, const float* __restrict__ g, const float* __restrict__ beta,
    float* __restrict__ out)
{
  int row = blockIdx.x*4 + (threadIdx.x >> 6);
  int lane = threadIdx.x & 63;
  const float* ap = A + (AMODE ? (long)(row>>2)*DM : (long)row*DM);
  float4 a = ld4(&ap[lane*4]);
  float4 b = ld4(&Bv[(long)row*DM + lane*4]);
  a.x+=b.x; a.y+=b.y; a.z+=b.z; a.w+=b.w;
  float sum = wave_sum(a.x+a.y+a.z+a.w);
  float sq  = wave_sum(a.x*a.x + a.y*a.y + a.z*a.z + a.w*a.w);
  float mean = sum * (1.f/DM);
  float var  = sq * (1.f/DM) - mean*mean;
  float inv = 1.0f / sqrtf(var + 1e-5f);
  float4 gg = ld4(&g[lane*4]);
  float4 bb = ld4(&beta[lane*4]);
  float4 ov;
  ov.x = (a.x-mean)*inv*gg.x + bb.x;
  ov.y = (a.y-mean)*inv*gg.y + bb.y;
  ov.z = (a.z-mean)*inv*gg.z + bb.z;
  ov.w = (a.w-mean)*inv*gg.w + bb.w;
  st4(&out[(long)row*DM + lane*4], ov);
}

__global__ __launch_bounds__(256) void moe_ln_kernel(const float* __restrict__ base,
    const float* __restrict__ yg, const float* __restrict__ scores, const int* __restrict__ rpos,
    const float* __restrict__ g, const float* __restrict__ beta, float* __restrict__ out)
{
  int row = blockIdx.x*4 + (threadIdx.x >> 6);
  int lane = threadIdx.x & 63;
  float s0 = scores[row*2], s1 = scores[row*2+1];
  int r0 = rpos[row*2], r1 = rpos[row*2+1];
  float4 a  = ld4(&base[(long)row*DM + lane*4]);
  float4 y0 = ld4(&yg[(long)r0*DM + lane*4]);
  float4 y1 = ld4(&yg[(long)r1*DM + lane*4]);
  a.x += s0*y0.x + s1*y1.x;
  a.y += s0*y0.y + s1*y1.y;
  a.z += s0*y0.z + s1*y1.z;
  a.w += s0*y0.w + s1*y1.w;
  float sum = wave_sum(a.x+a.y+a.z+a.w);
  float sq  = wave_sum(a.x*a.x + a.y*a.y + a.z*a.z + a.w*a.w);
  float mean = sum * (1.f/DM);
  float var  = sq * (1.f/DM) - mean*mean;
  float inv = 1.0f / sqrtf(var + 1e-5f);
  float4 gg = ld4(&g[lane*4]);
  float4 bb = ld4(&beta[lane*4]);
  float4 ov;
  ov.x = (a.x-mean)*inv*gg.x + bb.x;
  ov.y = (a.y-mean)*inv*gg.y + bb.y;
  ov.z = (a.z-mean)*inv*gg.z + bb.z;
  ov.w = (a.w-mean)*inv*gg.w + bb.w;
  st4(&out[(long)row*DM + lane*4], ov);
}

// ---------------- MoE gate ----------------
__global__ __launch_bounds__(256) void gate_kernel(const float* __restrict__ X,
    const float* __restrict__ GW, const float* __restrict__ GB,
    float* __restrict__ scores, int* __restrict__ topi, int* __restrict__ cnt)
{
  int row = blockIdx.x*4 + (threadIdx.x >> 6);
  int lane = threadIdx.x & 63;
  float4 x = ld4(&X[(long)row*DM + lane*4]);
  float lg[8];
  #pragma unroll
  for (int e=0; e<8; e++){
    float4 wv = ld4(&GW[e*DM + lane*4]);
    lg[e] = x.x*wv.x + x.y*wv.y + x.z*wv.z + x.w*wv.w;
  }
  #pragma unroll
  for (int mask=1; mask<64; mask<<=1){
    #pragma unroll
    for (int e=0; e<8; e++) lg[e] += __shfl_xor(lg[e], mask);
  }
  #pragma unroll
  for (int e=0; e<8; e++) lg[e] += GB[e];
  int i0 = 0; float v0 = lg[0];
  #pragma unroll
  for (int e=1; e<8; e++) if (lg[e] > v0){ v0 = lg[e]; i0 = e; }
  int i1 = -1; float v1 = -1e30f;
  #pragma unroll
  for (int e=0; e<8; e++) if (e != i0 && lg[e] > v1){ v1 = lg[e]; i1 = e; }
  if (lane == 0){
    float ee = expf(v1 - v0);
    float inv = 1.f/(1.f + ee);
    scores[row*2]   = inv;
    scores[row*2+1] = ee*inv;
    topi[row*2]   = i0;
    topi[row*2+1] = i1;
    atomicAdd(&cnt[i0], 1);
    atomicAdd(&cnt[i1], 1);
  }
}

__global__ void offs_kernel(const int* __restrict__ cnt, int* __restrict__ offs,
                            int* __restrict__ cnt2){
  if (threadIdx.x == 0){
    int o = 0;
    for (int e=0; e<8; e++){ offs[e] = o; o += cnt[e]; cnt2[e] = 0; }
  }
}

__global__ void assign_kernel(const int* __restrict__ topi, const int* __restrict__ offs,
    int* __restrict__ cnt2, int* __restrict__ map, int* __restrict__ rpos)
{
  int n = blockIdx.x*256 + threadIdx.x;
  if (n >= NTOK) return;
  for (int j=0; j<2; j++){
    int e = topi[n*2+j];
    int slot = atomicAdd(&cnt2[e], 1);
    int r = offs[e] + slot;
    map[r] = n;
    rpos[n*2+j] = r;
  }
}

__global__ void zero_ints(int* p, int n){
  int i = blockIdx.x*256 + threadIdx.x;
  if (i < n) p[i] = 0;
}

// =================================================================
extern "C" void kernel_launch(void* const* d_in, const int* in_sizes, int n_in,
                              void* d_out, int out_size, void* d_ws, size_t ws_size,
                              hipStream_t stream)
{
  const float* x      = (const float*)d_in[0];
  const float* Wi     = (const float*)d_in[1];
  const float* bi     = (const float*)d_in[2];
  const float* le     = (const float*)d_in[3];
  const float* Wqkv_s = (const float*)d_in[4];
  const float* bqkv_s = (const float*)d_in[5];
  const float* Wo_s   = (const float*)d_in[6];
  const float* bo_s   = (const float*)d_in[7];
  const float* Wqkv_c = (const float*)d_in[8];
  const float* bqkv_c = (const float*)d_in[9];
  const float* Wo_c   = (const float*)d_in[10];
  const float* bo_c   = (const float*)d_in[11];
  const float* ln_g   = (const float*)d_in[12];
  const float* ln_b   = (const float*)d_in[13];
  const float* gw1    = (const float*)d_in[14];
  const float* gb1    = (const float*)d_in[15];
  const float* W1a    = (const float*)d_in[16];
  const float* b1a    = (const float*)d_in[17];
  const float* W2a    = (const float*)d_in[18];
  const float* b2a    = (const float*)d_in[19];
  const float* gw2    = (const float*)d_in[20];
  const float* gb2    = (const float*)d_in[21];
  const float* W1b    = (const float*)d_in[22];
  const float* b1b    = (const float*)d_in[23];
  const float* W2b    = (const float*)d_in[24];
  const float* b2b    = (const float*)d_in[25];
  const float* Wout   = (const float*)d_in[26];
  const float* bout   = (const float*)d_in[27];

  float* w = (float*)d_ws;
  const long SZ = 1048576;            // NTOK*DM
  float* pos  = w;                    // 262144
  float* src  = pos  + 262144;
  float* t2s  = src  + SZ;
  float* tgtA = t2s  + SZ;
  float* dec  = tgtA + SZ;
  float* od   = dec  + SZ;
  float* od2  = od   + SZ;
  float* yg   = od2  + SZ;            // 2,097,152 fp32
  float* scores = yg + 2097152;       // 8192
  // pre-split MoE weights: 8 planes x 2,097,152 u16
  u16* wsp  = (u16*)(scores + 8192);
  u16* W1ah = wsp;             u16* W1al = wsp + 2097152;
  u16* W1bh = wsp + 4194304;   u16* W1bl = wsp + 6291456;
  u16* W2ah = wsp + 8388608;   u16* W2al = wsp + 10485760;
  u16* W2bh = wsp + 12582912;  u16* W2bl = wsp + 14680064;
  // overlay region R: 8,388,608 floats
  float* R   = scores + 8192 + 8388608;
  float* tok = R;                     // dead before encp written
  float* encp= R;
  float* tp  = R + SZ;
  float* decp= R + 2*SZ;
  float* q   = R + 3*SZ;
  float* k   = R + 4*SZ;
  float* v   = R + 5*SZ;              // also reused as t2c
  float* ao  = R + 6*SZ;
  u32*  hg   = (u32*)R;               // packed pairs (MoE phase; q..ao dead)
  float* rec = R;                     // final (hg dead)
  int* ip   = (int*)(R + 8388608);
  int* topi = ip;                     // 8192
  int* map  = ip + 8192;              // 8192
  int* rpos = ip + 16384;             // 8192
  int* cnts = ip + 24576;             // 4 sets * 24 ints

  dim3 blk(256);
  dim3 gDense(128, 4, 1);             // 4096/32 x 256/64
  dim3 gQKV(128, 4, 3);

  zero_ints<<<1, 128, 0, stream>>>(cnts, 96);
  pos_kernel<<<NHW, DM, 0, stream>>>(pos);
  tin_kernel<<<(NTOK*NCIN + 255)/256, blk, 0, stream>>>(x, tok);

  // one-time MoE weight transpose+split
  tconv_kernel<<<dim3(32, 8, 8), blk, 0, stream>>>(W1a, W1ah, W1al, DM,   NDFF);
  tconv_kernel<<<dim3(32, 8, 8), blk, 0, stream>>>(W1b, W1bh, W1bl, DM,   NDFF);
  tconv_kernel<<<dim3(8, 32, 8), blk, 0, stream>>>(W2a, W2ah, W2al, NDFF, DM);
  tconv_kernel<<<dim3(8, 32, 8), blk, 0, stream>>>(W2b, W2bh, W2bl, NDFF, DM);

  // src = tok @ Wi^T + bi   (K=272)
  sgemm<false,false,0,0,false,0,false><<<gDense, blk, 0, stream>>>(
      tok, nullptr, nullptr, NCIN, Wi, nullptr, NCIN, bi, src, nullptr, nullptr, DM,
      NTOK, DM, NCIN, nullptr, nullptr, nullptr, 0, 0);

  addpos_kernel<0><<<1024, blk, 0, stream>>>(src, pos, encp);
  addpos_kernel<1><<<1024, blk, 0, stream>>>(le, pos, tp);

  // self-attention MHA (layer-invariant, hoisted): batched QKV
  sgemm<false,false,0,0,false,0,true><<<gQKV, blk, 0, stream>>>(
      tp, encp, src, DM, Wqkv_s, nullptr, DM, bqkv_s, q, k, v, DM,
      NTOK, DM, DM, nullptr, nullptr, nullptr, 0, 0);
  attn_kernel<<<dim3(32,32), blk, 0, stream>>>(q, k, v, ao);
  sgemm<false,false,0,0,false,0,false><<<gDense, blk, 0, stream>>>(
      ao, nullptr, nullptr, DM, Wo_s, nullptr, DM, bo_s, t2s, nullptr, nullptr, DM,
      NTOK, DM, DM, nullptr, nullptr, nullptr, 0, 0);

  const float* decIn = src;
  for (int i = 0; i < 2; i++){
    add_ln_kernel<1><<<1024, blk, 0, stream>>>(le, t2s, ln_g + (4*i)*DM, ln_b + (4*i)*DM, tgtA);
    addpos_kernel<0><<<1024, blk, 0, stream>>>(tgtA, pos, tp);
    addpos_kernel<0><<<1024, blk, 0, stream>>>(decIn, pos, decp);
    sgemm<false,false,0,0,false,0,true><<<gQKV, blk, 0, stream>>>(
        tp, decp, decIn, DM, Wqkv_c, nullptr, DM, bqkv_c, q, k, v, DM,
        NTOK, DM, DM, nullptr, nullptr, nullptr, 0, 0);
    attn_kernel<<<dim3(32,32), blk, 0, stream>>>(q, k, v, ao);
    sgemm<false,false,0,0,false,0,false><<<gDense, blk, 0, stream>>>(
        ao, nullptr, nullptr, DM, Wo_c, nullptr, DM, bo_c, v, nullptr, nullptr, DM,
        NTOK, DM, DM, nullptr, nullptr, nullptr, 0, 0);   // t2c -> v
    add_ln_kernel<0><<<1024, blk, 0, stream>>>(tgtA, v, ln_g + (4*i+1)*DM, ln_b + (4*i+1)*DM, od);

    // ---- MoE a ----
    {
      int* cnt  = cnts + (i*2)*24;
      int* cnt2 = cnt + 8;
      int* offs = cnt + 16;
      gate_kernel<<<1024, blk, 0, stream>>>(od, gw1, gb1, scores, topi, cnt);
      offs_kernel<<<1, 64, 0, stream>>>(cnt, offs, cnt2);
      assign_kernel<<<16, blk, 0, stream>>>(topi, offs, cnt2, map, rpos);
      sgemm<true,true,0,1,true,1,false><<<dim3(256,16,8), blk, 0, stream>>>(
          od, nullptr, nullptr, DM, W1ah, W1al, DM, b1a, hg, nullptr, nullptr, NDFF,
          0, NDFF, DM, map, cnt, offs, 262144L, NDFF);
      sgemm<true,false,1,1,false,0,false><<<dim3(256,4,8), blk, 0, stream>>>(
          hg, nullptr, nullptr, NDFF, W2ah, W2al, NDFF, b2a, yg, nullptr, nullptr, DM,
          0, DM, NDFF, nullptr, cnt, offs, 262144L, DM);
      moe_ln_kernel<<<1024, blk, 0, stream>>>(od, yg, scores, rpos,
          ln_g + (4*i+2)*DM, ln_b + (4*i+2)*DM, od2);
    }
    // ---- MoE b ----
    {
      int* cnt  = cnts + (i*2+1)*24;
      int* cnt2 = cnt + 8;
      int* offs = cnt + 16;
      gate_kernel<<<1024, blk, 0, stream>>>(od2, gw2, gb2, scores, topi, cnt);
      offs_kernel<<<1, 64, 0, stream>>>(cnt, offs, cnt2);
      assign_kernel<<<16, blk, 0, stream>>>(topi, offs, cnt2, map, rpos);
      sgemm<true,true,0,1,true,1,false><<<dim3(256,16,8), blk, 0, stream>>>(
          od2, nullptr, nullptr, DM, W1bh, W1bl, DM, b1b, hg, nullptr, nullptr, NDFF,
          0, NDFF, DM, map, cnt, offs, 262144L, NDFF);
      sgemm<true,false,1,1,false,0,false><<<dim3(256,4,8), blk, 0, stream>>>(
          hg, nullptr, nullptr, NDFF, W2bh, W2bl, NDFF, b2b, yg, nullptr, nullptr, DM,
          0, DM, NDFF, nullptr, cnt, offs, 262144L, DM);
      moe_ln_kernel<<<1024, blk, 0, stream>>>(od2, yg, scores, rpos,
          ln_g + (4*i+3)*DM, ln_b + (4*i+3)*DM, dec);
    }
    decIn = dec;
  }

  // rec = dec @ Wout^T + bout   [4096, 272]
  sgemm<false,false,0,0,false,0,false><<<dim3(128,5,1), blk, 0, stream>>>(
      dec, nullptr, nullptr, DM, Wout, nullptr, DM, bout, rec, nullptr, nullptr, NCIN,
      NTOK, NCIN, DM, nullptr, nullptr, nullptr, 0, 0);
  tout_kernel<<<(NTOK*NCIN + 255)/256, blk, 0, stream>>>(rec, (float*)d_out);
}

// Round 6
// 1385.929 us; speedup vs baseline: 1.7295x; 1.2040x over previous
//
#include <hip/hip_runtime.h>

#define NHW 1024
#define NB 4
#define DM 256
#define NTOK 4096      // NHW * NB
#define NCIN 272
#define NDFF 1024

typedef unsigned short u16;
typedef unsigned int u32;
typedef __attribute__((ext_vector_type(8))) short s16x8;
typedef __attribute__((ext_vector_type(4))) float f32x4;

static const int GEMM_SMEM = (32+32+64+64)*56*2;   // 21504 B dynamic LDS

__device__ __forceinline__ float4 ld4(const float* p){ return *(const float4*)p; }
__device__ __forceinline__ void st4(float* p, float4 v){ *(float4*)p = v; }

// split fp32 -> bf16 hi + bf16 lo  (hi = RNE(x); lo = RNE(x - hi))
__device__ __forceinline__ void splitf(float x, u16& h, u16& l){
  u32 u = __float_as_uint(x);
  u32 hu = (u + (0x7FFFu + ((u >> 16) & 1u))) >> 16;
  h = (u16)hu;
  float hf = __uint_as_float(hu << 16);
  float r = x - hf;
  u32 v = __float_as_uint(r);
  v += 0x7FFFu + ((v >> 16) & 1u);
  l = (u16)(v >> 16);
}

// ---------------- positional embedding ----------------
__global__ void pos_kernel(float* __restrict__ pos){
  int s = blockIdx.x, d = threadIdx.x;
  int row = s >> 5, col = s & 31;
  float base = (d < 128) ? (float)(row + 1) : (float)(col + 1);
  float val = base / (32.0f + 1e-6f) * 6.2831853071795864f;
  int dd = (d < 128) ? d : d - 128;
  int mf = dd >> 1;
  float f = powf(10000.0f, (float)mf * (1.0f/64.0f));
  float a = val / f;
  pos[s*DM + d] = (dd & 1) ? cosf(a) : sinf(a);
}

// ---------------- transposes ----------------
__global__ void tin_kernel(const float* __restrict__ x, float* __restrict__ tok){
  int idx = blockIdx.x*256 + threadIdx.x;
  if (idx >= NTOK*NCIN) return;
  int c = idx % NCIN;
  int n = idx / NCIN;
  int s = n >> 2, b = n & 3;
  tok[idx] = x[((long)(b*NCIN + c))*NHW + s];
}
__global__ void tout_kernel(const float* __restrict__ rec, float* __restrict__ out){
  int idx = blockIdx.x*256 + threadIdx.x;
  if (idx >= NTOK*NCIN) return;
  int s = idx & (NHW-1);
  int bc = idx >> 10;
  int b = bc / NCIN, c = bc % NCIN;
  out[idx] = rec[((long)(s*NB + b))*NCIN + c];
}

// -------- weight transpose+split: in [K][N] fp32 -> hi/lo planes [N][K] bf16 --------
__global__ __launch_bounds__(256) void tconv_kernel(const float* __restrict__ in,
    u16* __restrict__ oh, u16* __restrict__ ol, int K, int N){
  __shared__ float tile[32][33];
  long base = (long)blockIdx.z * (long)K * (long)N;
  int k0 = blockIdx.y*32, n0 = blockIdx.x*32;
  int tx = threadIdx.x & 31, ty = threadIdx.x >> 5;   // ty 0..7
  #pragma unroll
  for (int i=0;i<32;i+=8)
    tile[ty+i][tx] = in[base + (long)(k0+ty+i)*N + n0+tx];
  __syncthreads();
  #pragma unroll
  for (int i=0;i<32;i+=8){
    float v = tile[tx][ty+i];
    u16 h,l; splitf(v,h,l);
    long o = base + (long)(n0+ty+i)*K + k0+tx;
    oh[o]=h; ol[o]=l;
  }
}

// ---------------- split-bf16 MFMA GEMM body (3-term) ----------------
// Tile 32x64, BK=32, 256 threads = 4 waves; wave computes 16x32.
// ASRC 0: A fp32. 1: A packed hi|lo u32. 2: A fp32 + pos[n>>2]. 3: A fp32 s-indexed + pos.
// BSRC 0: B fp32 [N][ldb]. 1: B pre-split hi/lo planes u16.
// CDST 0: C fp32. 1: C packed u32 pairs.
template<bool GROUPED, bool INDIRECT, int ASRC, int BSRC, bool RELU, int CDST>
__device__ __forceinline__ void sgemm_body(
    const void* __restrict__ Av, int lda,
    const float* __restrict__ pos,
    const void* __restrict__ Bv, const void* __restrict__ Bv2, int ldb,
    const float* __restrict__ bias,
    void* __restrict__ Cv, int ldc,
    int M, int N, int K,
    const int* __restrict__ map,
    const int* __restrict__ cnt,
    const int* __restrict__ offs,
    long strideB, int strideBias, int e)
{
  int rows = GROUPED ? cnt[e] : M;
  int bm = blockIdx.x, bn = blockIdx.y;
  if (bm*32 >= rows) return;
  int row0 = GROUPED ? offs[e] : 0;
  const float* Af = (const float*)Av;
  const u32*   Ap = (const u32*)Av;
  const float* Bf = (const float*)Bv;
  const u16*   Bhp = (const u16*)Bv;
  const u16*   Blp = (const u16*)Bv2;
  if (GROUPED && BSRC==1){ Bhp += (long)e*strideB; Blp += (long)e*strideB; }
  const float* biasp = bias ? (GROUPED ? bias + (long)e*strideBias : bias) : nullptr;

  extern __shared__ u16 smem[];
  u16* Ah = smem;                 // 32*56
  u16* Al = Ah + 32*56;
  u16* Bh = Al + 32*56;           // 64*56
  u16* Bl = Bh + 64*56;

  int tid = threadIdx.x;
  int w = tid >> 6, ln = tid & 63;
  int wm = w >> 1, wn = w & 1;
  int lr = ln & 15, lh = ln >> 4;
  int srow = tid >> 2, sseg = tid & 3;

  int bgrow = bn*64 + srow;
  bool bok = bgrow < N;
  int agrow = bm*32 + srow;
  bool aok = (tid < 128) && (agrow < rows);
  long arow = 0;
  if (aok) arow = INDIRECT ? (long)map[row0 + agrow] : (long)(row0 + agrow);

  const f32x4 z4 = {0.f,0.f,0.f,0.f};
  f32x4 acc0 = z4, acc1 = z4;
  const s16x8 z8 = {0,0,0,0,0,0,0,0};

  for (int k0 = 0; k0 < K; k0 += 32){
    int kk = k0 + sseg*8;
    bool kok = kk < K;                 // K % 8 == 0 always
    s16x8 hv = z8, lv = z8;
    if (bok && kok){
      if (BSRC == 0){
        float4 x0 = ld4(&Bf[(long)bgrow*ldb + kk]);
        float4 x1 = ld4(&Bf[(long)bgrow*ldb + kk + 4]);
        float xs[8] = {x0.x,x0.y,x0.z,x0.w,x1.x,x1.y,x1.z,x1.w};
        #pragma unroll
        for (int t=0;t<8;t++){ u16 hh,ll; splitf(xs[t],hh,ll); hv[t]=(short)hh; lv[t]=(short)ll; }
      } else {
        hv = *(const s16x8*)&Bhp[(long)bgrow*ldb + kk];
        lv = *(const s16x8*)&Blp[(long)bgrow*ldb + kk];
      }
    }
    *(s16x8*)&Bh[srow*56 + sseg*8] = hv;
    *(s16x8*)&Bl[srow*56 + sseg*8] = lv;
    if (tid < 128){
      hv = z8; lv = z8;
      if (aok && kok){
        if (ASRC == 1){
          uint4 p0 = *(const uint4*)&Ap[arow*lda + kk];
          uint4 p1 = *(const uint4*)&Ap[arow*lda + kk + 4];
          u32 ws[8] = {p0.x,p0.y,p0.z,p0.w,p1.x,p1.y,p1.z,p1.w};
          #pragma unroll
          for (int t=0;t<8;t++){ hv[t]=(short)(ws[t]&0xFFFFu); lv[t]=(short)(ws[t]>>16); }
        } else {
          long aoff = (ASRC==3 ? (long)(arow>>2) : arow)*lda + kk;
          float4 x0 = ld4(&Af[aoff]);
          float4 x1 = ld4(&Af[aoff + 4]);
          if (ASRC==2 || ASRC==3){
            long poff = (long)(arow>>2)*DM + kk;
            float4 p0 = ld4(&pos[poff]);
            float4 p1 = ld4(&pos[poff + 4]);
            x0.x+=p0.x; x0.y+=p0.y; x0.z+=p0.z; x0.w+=p0.w;
            x1.x+=p1.x; x1.y+=p1.y; x1.z+=p1.z; x1.w+=p1.w;
          }
          float xs[8] = {x0.x,x0.y,x0.z,x0.w,x1.x,x1.y,x1.z,x1.w};
          #pragma unroll
          for (int t=0;t<8;t++){ u16 hh,ll; splitf(xs[t],hh,ll); hv[t]=(short)hh; lv[t]=(short)ll; }
        }
      }
      *(s16x8*)&Ah[srow*56 + sseg*8] = hv;
      *(s16x8*)&Al[srow*56 + sseg*8] = lv;
    }
    __syncthreads();
    s16x8 a0h = *(const s16x8*)&Ah[(wm*16 + lr)*56 + lh*8];
    s16x8 a0l = *(const s16x8*)&Al[(wm*16 + lr)*56 + lh*8];
    s16x8 b0h = *(const s16x8*)&Bh[(wn*32      + lr)*56 + lh*8];
    s16x8 b1h = *(const s16x8*)&Bh[(wn*32 + 16 + lr)*56 + lh*8];
    s16x8 b0l = *(const s16x8*)&Bl[(wn*32      + lr)*56 + lh*8];
    s16x8 b1l = *(const s16x8*)&Bl[(wn*32 + 16 + lr)*56 + lh*8];
    acc0 = __builtin_amdgcn_mfma_f32_16x16x32_bf16(a0h, b0h, acc0, 0,0,0);
    acc1 = __builtin_amdgcn_mfma_f32_16x16x32_bf16(a0h, b1h, acc1, 0,0,0);
    acc0 = __builtin_amdgcn_mfma_f32_16x16x32_bf16(a0h, b0l, acc0, 0,0,0);
    acc1 = __builtin_amdgcn_mfma_f32_16x16x32_bf16(a0h, b1l, acc1, 0,0,0);
    acc0 = __builtin_amdgcn_mfma_f32_16x16x32_bf16(a0l, b0h, acc0, 0,0,0);
    acc1 = __builtin_amdgcn_mfma_f32_16x16x32_bf16(a0l, b1h, acc1, 0,0,0);
    __syncthreads();
  }

  int c0 = bn*64 + wn*32 + lr;
  int c1 = c0 + 16;
  float bv0 = (biasp && c0 < N) ? biasp[c0] : 0.f;
  float bv1 = (biasp && c1 < N) ? biasp[c1] : 0.f;
  int rbase = bm*32 + wm*16 + lh*4;
  auto stc = [&](int gr, int gc, float vv){
    if (gr < rows && gc < N){
      float t = RELU ? fmaxf(vv, 0.f) : vv;
      if (CDST == 1){
        u16 h,l; splitf(t,h,l);
        ((u32*)Cv)[(long)(row0+gr)*ldc + gc] = (u32)h | ((u32)l << 16);
      } else {
        ((float*)Cv)[(long)(row0+gr)*ldc + gc] = t;
      }
    }
  };
  #pragma unroll
  for (int r = 0; r < 4; r++){
    stc(rbase + r, c0, acc0[r] + bv0);
    stc(rbase + r, c1, acc1[r] + bv1);
  }
}

// ---- named GEMM wrappers (distinct rocprof rows) ----
__global__ __launch_bounds__(256) void gemm_plain(const float* A, int lda,
    const float* B, int ldb, const float* bias, float* C, int ldc, int M, int N, int K){
  sgemm_body<false,false,0,0,false,0>(A, lda, nullptr, B, nullptr, ldb, bias, C, ldc,
      M, N, K, nullptr, nullptr, nullptr, 0, 0, 0);
}

__global__ __launch_bounds__(256) void gemm_qkv(const float* Aq, int mq,
    const float* Ak, int mk, const float* Avv, const float* pos,
    const float* Bw, const float* bias, float* Cq, float* Ck, float* Cvv){
  int z = blockIdx.z;
  const float* A = z==0 ? Aq : (z==1 ? Ak : Avv);
  float* C = z==0 ? Cq : (z==1 ? Ck : Cvv);
  const float* Bp = Bw + (long)z*256*DM;
  const float* bp = bias + z*256;
  int mode = z==0 ? mq : (z==1 ? mk : 0);
  if (mode == 3)
    sgemm_body<false,false,3,0,false,0>(A, DM, pos, Bp, nullptr, DM, bp, C, DM,
        NTOK, DM, DM, nullptr, nullptr, nullptr, 0, 0, 0);
  else if (mode == 2)
    sgemm_body<false,false,2,0,false,0>(A, DM, pos, Bp, nullptr, DM, bp, C, DM,
        NTOK, DM, DM, nullptr, nullptr, nullptr, 0, 0, 0);
  else
    sgemm_body<false,false,0,0,false,0>(A, DM, pos, Bp, nullptr, DM, bp, C, DM,
        NTOK, DM, DM, nullptr, nullptr, nullptr, 0, 0, 0);
}

__global__ __launch_bounds__(256) void gemm_moe1(const float* A, const u16* Bh_, const u16* Bl_,
    const float* bias, u32* C, const int* map, const int* cnt, const int* offs){
  sgemm_body<true,true,0,1,true,1>(A, DM, nullptr, Bh_, Bl_, DM, bias, C, NDFF,
      0, NDFF, DM, map, cnt, offs, 262144L, NDFF, blockIdx.z);
}

__global__ __launch_bounds__(256) void gemm_moe2(const u32* A, const u16* Bh_, const u16* Bl_,
    const float* bias, float* C, const int* cnt, const int* offs){
  sgemm_body<true,false,1,1,false,0>(A, NDFF, nullptr, Bh_, Bl_, NDFF, bias, C, DM,
      0, DM, NDFF, nullptr, cnt, offs, 262144L, DM, blockIdx.z);
}

// ---------------- flash attention, fp32, dh=32, S=T=1024 ----------------
// grid (16 qtiles of 64 rows, 32 bh); block 256 = 32 row-pairs x 8 lanes.
__global__ __launch_bounds__(256) void attn_kernel(const float* __restrict__ Q,
    const float* __restrict__ Kb, const float* __restrict__ Vb, float* __restrict__ O)
{
  __shared__ float Ks[64][36];
  __shared__ float Vs[64][36];
  int qt = blockIdx.x, bh = blockIdx.y;
  int b = bh >> 3, h = bh & 7;
  int tid = threadIdx.x;
  int rl = tid >> 3, sub = tid & 7;
  long qr0 = ((long)((qt*64 + rl)*NB + b))*DM + h*32;
  long qr1 = ((long)((qt*64 + 32 + rl)*NB + b))*DM + h*32;
  const float scale = 0.17677669529663687f;   // 1/sqrt(32)
  float q0[32], q1[32], o0[32], o1[32];
  float m0 = -1e30f, l0 = 0.f, m1 = -1e30f, l1 = 0.f;
  #pragma unroll
  for (int d=0; d<32; d+=4){
    float4 t = ld4(&Q[qr0 + d]);
    q0[d]=t.x*scale; q0[d+1]=t.y*scale; q0[d+2]=t.z*scale; q0[d+3]=t.w*scale;
    t = ld4(&Q[qr1 + d]);
    q1[d]=t.x*scale; q1[d+1]=t.y*scale; q1[d+2]=t.z*scale; q1[d+3]=t.w*scale;
    o0[d]=0.f; o0[d+1]=0.f; o0[d+2]=0.f; o0[d+3]=0.f;
    o1[d]=0.f; o1[d+1]=0.f; o1[d+2]=0.f; o1[d+3]=0.f;
  }
  for (int kt=0; kt<16; kt++){
    __syncthreads();
    #pragma unroll
    for (int i=0;i<2;i++){
      int fidx = tid*2 + i;
      int r = fidx >> 3, d4 = (fidx & 7) << 2;
      long g = ((long)((kt*64 + r)*NB + b))*DM + h*32 + d4;
      st4(&Ks[r][d4], ld4(&Kb[g]));
      st4(&Vs[r][d4], ld4(&Vb[g]));
    }
    __syncthreads();
    float s0[8], s1[8];
    #pragma unroll
    for (int j=0;j<8;j++){
      int c = (j<<3) + sub;
      float a0 = 0.f, a1 = 0.f;
      #pragma unroll
      for (int d=0; d<32; d+=4){
        float4 kv = ld4(&Ks[c][d]);
        a0 += q0[d]*kv.x + q0[d+1]*kv.y + q0[d+2]*kv.z + q0[d+3]*kv.w;
        a1 += q1[d]*kv.x + q1[d+1]*kv.y + q1[d+2]*kv.z + q1[d+3]*kv.w;
      }
      s0[j] = a0; s1[j] = a1;
    }
    float tm0 = s0[0], tm1 = s1[0];
    #pragma unroll
    for (int j=1;j<8;j++){ tm0 = fmaxf(tm0, s0[j]); tm1 = fmaxf(tm1, s1[j]); }
    if (tm0 > m0){                       // alpha==1 skip is exact
      float al = __expf(m0 - tm0);       // note: rescale old state by exp(m_old-m_new)
      l0 *= al;
      #pragma unroll
      for (int d=0; d<32; d++) o0[d] *= al;
      m0 = tm0;
    }
    if (tm1 > m1){
      float al = __expf(m1 - tm1);
      l1 *= al;
      #pragma unroll
      for (int d=0; d<32; d++) o1[d] *= al;
      m1 = tm1;
    }
    #pragma unroll
    for (int j=0;j<8;j++){
      float p0 = __expf(s0[j] - m0);
      float p1 = __expf(s1[j] - m1);
      l0 += p0; l1 += p1;
      int c = (j<<3) + sub;
      #pragma unroll
      for (int d=0; d<32; d+=4){
        float4 vv = ld4(&Vs[c][d]);
        o0[d]   += p0*vv.x; o0[d+1] += p0*vv.y; o0[d+2] += p0*vv.z; o0[d+3] += p0*vv.w;
        o1[d]   += p1*vv.x; o1[d+1] += p1*vv.y; o1[d+2] += p1*vv.z; o1[d+3] += p1*vv.w;
      }
    }
  }
  // merge the 8 partial states (key-range split) across sub=0..7
  #pragma unroll
  for (int mask=1; mask<=4; mask<<=1){
    float m2 = __shfl_xor(m0, mask), l2 = __shfl_xor(l0, mask);
    float M = fmaxf(m0, m2);
    float a1f = __expf(m0 - M), a2f = __expf(m2 - M);
    l0 = a1f*l0 + a2f*l2;
    #pragma unroll
    for (int d=0; d<32; d++){
      float ox = __shfl_xor(o0[d], mask);
      o0[d] = a1f*o0[d] + a2f*ox;
    }
    m0 = M;
    m2 = __shfl_xor(m1, mask); l2 = __shfl_xor(l1, mask);
    M = fmaxf(m1, m2);
    a1f = __expf(m1 - M); a2f = __expf(m2 - M);
    l1 = a1f*l1 + a2f*l2;
    #pragma unroll
    for (int d=0; d<32; d++){
      float ox = __shfl_xor(o1[d], mask);
      o1[d] = a1f*o1[d] + a2f*ox;
    }
    m1 = M;
  }
  float i0 = 1.f/l0, i1 = 1.f/l1;
  float4 t0, t1;
  switch(sub){
    case 0: t0=make_float4(o0[0],o0[1],o0[2],o0[3]);     t1=make_float4(o1[0],o1[1],o1[2],o1[3]);     break;
    case 1: t0=make_float4(o0[4],o0[5],o0[6],o0[7]);     t1=make_float4(o1[4],o1[5],o1[6],o1[7]);     break;
    case 2: t0=make_float4(o0[8],o0[9],o0[10],o0[11]);   t1=make_float4(o1[8],o1[9],o1[10],o1[11]);   break;
    case 3: t0=make_float4(o0[12],o0[13],o0[14],o0[15]); t1=make_float4(o1[12],o1[13],o1[14],o1[15]); break;
    case 4: t0=make_float4(o0[16],o0[17],o0[18],o0[19]); t1=make_float4(o1[16],o1[17],o1[18],o1[19]); break;
    case 5: t0=make_float4(o0[20],o0[21],o0[22],o0[23]); t1=make_float4(o1[20],o1[21],o1[22],o1[23]); break;
    case 6: t0=make_float4(o0[24],o0[25],o0[26],o0[27]); t1=make_float4(o1[24],o1[25],o1[26],o1[27]); break;
    default:t0=make_float4(o0[28],o0[29],o0[30],o0[31]); t1=make_float4(o1[28],o1[29],o1[30],o1[31]); break;
  }
  t0.x*=i0; t0.y*=i0; t0.z*=i0; t0.w*=i0;
  t1.x*=i1; t1.y*=i1; t1.z*=i1; t1.w*=i1;
  st4(&O[qr0 + sub*4], t0);
  st4(&O[qr1 + sub*4], t1);
}

// ---------------- LN / gate helpers ----------------
__device__ __forceinline__ float wave_sum(float v){
  #pragma unroll
  for (int m=1; m<64; m<<=1) v += __shfl_xor(v, m);
  return v;
}

__device__ __forceinline__ float4 ln_finish(float4 a, const float* g, const float* beta, int lane){
  float sum = wave_sum(a.x+a.y+a.z+a.w);
  float sq  = wave_sum(a.x*a.x + a.y*a.y + a.z*a.z + a.w*a.w);
  float mean = sum * (1.f/DM);
  float var  = sq * (1.f/DM) - mean*mean;
  float inv = 1.0f / sqrtf(var + 1e-5f);
  float4 gg = ld4(&g[lane*4]);
  float4 bb = ld4(&beta[lane*4]);
  float4 ov;
  ov.x = (a.x-mean)*inv*gg.x + bb.x;
  ov.y = (a.y-mean)*inv*gg.y + bb.y;
  ov.z = (a.z-mean)*inv*gg.z + bb.z;
  ov.w = (a.w-mean)*inv*gg.w + bb.w;
  return ov;
}

__device__ __forceinline__ void gate_from_regs(float4 ov, int row, int lane,
    const float* GW, const float* GB, float* scores, int* topi, int* cnt){
  float lg[8];
  #pragma unroll
  for (int e=0; e<8; e++){
    float4 wv = ld4(&GW[e*DM + lane*4]);
    lg[e] = ov.x*wv.x + ov.y*wv.y + ov.z*wv.z + ov.w*wv.w;
  }
  #pragma unroll
  for (int mask=1; mask<64; mask<<=1){
    #pragma unroll
    for (int e=0; e<8; e++) lg[e] += __shfl_xor(lg[e], mask);
  }
  #pragma unroll
  for (int e=0; e<8; e++) lg[e] += GB[e];
  int i0 = 0; float v0 = lg[0];
  #pragma unroll
  for (int e=1; e<8; e++) if (lg[e] > v0){ v0 = lg[e]; i0 = e; }
  int i1 = -1; float v1 = -1e30f;
  #pragma unroll
  for (int e=0; e<8; e++) if (e != i0 && lg[e] > v1){ v1 = lg[e]; i1 = e; }
  if (lane == 0){
    float ee = expf(v1 - v0);
    float inv = 1.f/(1.f + ee);
    scores[row*2]   = inv;
    scores[row*2+1] = ee*inv;
    topi[row*2]   = i0;
    topi[row*2+1] = i1;
    atomicAdd(&cnt[i0], 1);
    atomicAdd(&cnt[i1], 1);
  }
}

// plain add+LN (AMODE 1: A s-indexed broadcast, e.g. learned_embed)
template<int AMODE>
__global__ __launch_bounds__(256) void add_ln_kernel(const float* __restrict__ A,
    const float* __restrict__ Bv, const float* __restrict__ g, const float* __restrict__ beta,
    float* __restrict__ out)
{
  int row = blockIdx.x*4 + (threadIdx.x >> 6);
  int lane = threadIdx.x & 63;
  const float* ap = A + (AMODE ? (long)(row>>2)*DM : (long)row*DM);
  float4 a = ld4(&ap[lane*4]);
  float4 b = ld4(&Bv[(long)row*DM + lane*4]);
  a.x+=b.x; a.y+=b.y; a.z+=b.z; a.w+=b.w;
  float4 ov = ln_finish(a, g, beta, lane);
  st4(&out[(long)row*DM + lane*4], ov);
}

// add+LN fused with gate
__global__ __launch_bounds__(256) void add_ln_gate(const float* __restrict__ A,
    const float* __restrict__ Bv, const float* __restrict__ g, const float* __restrict__ beta,
    float* __restrict__ out, const float* __restrict__ GW, const float* __restrict__ GB,
    float* __restrict__ scores, int* __restrict__ topi, int* __restrict__ cnt)
{
  int row = blockIdx.x*4 + (threadIdx.x >> 6);
  int lane = threadIdx.x & 63;
  float4 a = ld4(&A[(long)row*DM + lane*4]);
  float4 b = ld4(&Bv[(long)row*DM + lane*4]);
  a.x+=b.x; a.y+=b.y; a.z+=b.z; a.w+=b.w;
  float4 ov = ln_finish(a, g, beta, lane);
  st4(&out[(long)row*DM + lane*4], ov);
  gate_from_regs(ov, row, lane, GW, GB, scores, topi, cnt);
}

// MoE combine + LN (+ optional gate for next MoE)
template<bool GATE>
__global__ __launch_bounds__(256) void moe_ln_kernel(const float* __restrict__ base,
    const float* __restrict__ yg, const float* __restrict__ scores, const int* __restrict__ rpos,
    const float* __restrict__ g, const float* __restrict__ beta, float* __restrict__ out,
    const float* __restrict__ GW, const float* __restrict__ GB,
    float* __restrict__ scores2, int* __restrict__ topi2, int* __restrict__ cnt2)
{
  int row = blockIdx.x*4 + (threadIdx.x >> 6);
  int lane = threadIdx.x & 63;
  float s0 = scores[row*2], s1 = scores[row*2+1];
  int r0 = rpos[row*2], r1 = rpos[row*2+1];
  float4 a  = ld4(&base[(long)row*DM + lane*4]);
  float4 y0 = ld4(&yg[(long)r0*DM + lane*4]);
  float4 y1 = ld4(&yg[(long)r1*DM + lane*4]);
  a.x += s0*y0.x + s1*y1.x;
  a.y += s0*y0.y + s1*y1.y;
  a.z += s0*y0.z + s1*y1.z;
  a.w += s0*y0.w + s1*y1.w;
  float4 ov = ln_finish(a, g, beta, lane);
  st4(&out[(long)row*DM + lane*4], ov);
  if (GATE) gate_from_regs(ov, row, lane, GW, GB, scores2, topi2, cnt2);
}

// offsets + slot assignment in one block (LDS counters)
__global__ void offs_assign(const int* __restrict__ cnt, int* __restrict__ offs_g,
    const int* __restrict__ topi, int* __restrict__ map, int* __restrict__ rpos)
{
  __shared__ int offs[8];
  __shared__ int c2[8];
  if (threadIdx.x == 0){
    int o = 0;
    #pragma unroll
    for (int e=0; e<8; e++){ offs[e] = o; o += cnt[e]; }
  }
  if (threadIdx.x < 8) c2[threadIdx.x] = 0;
  __syncthreads();
  for (int n = threadIdx.x; n < NTOK; n += 256){
    #pragma unroll
    for (int j=0; j<2; j++){
      int e = topi[n*2+j];
      int slot = atomicAdd(&c2[e], 1);
      int r = offs[e] + slot;
      map[r] = n;
      rpos[n*2+j] = r;
    }
  }
  if (threadIdx.x < 8) offs_g[threadIdx.x] = offs[threadIdx.x];
}

__global__ void zero_ints(int* p, int n){
  int i = blockIdx.x*256 + threadIdx.x;
  if (i < n) p[i] = 0;
}

// =================================================================
extern "C" void kernel_launch(void* const* d_in, const int* in_sizes, int n_in,
                              void* d_out, int out_size, void* d_ws, size_t ws_size,
                              hipStream_t stream)
{
  const float* x      = (const float*)d_in[0];
  const float* Wi     = (const float*)d_in[1];
  const float* bi     = (const float*)d_in[2];
  const float* le     = (const float*)d_in[3];
  const float* Wqkv_s = (const float*)d_in[4];
  const float* bqkv_s = (const float*)d_in[5];
  const float* Wo_s   = (const float*)d_in[6];
  const float* bo_s   = (const float*)d_in[7];
  const float* Wqkv_c = (const float*)d_in[8];
  const float* bqkv_c = (const float*)d_in[9];
  const float* Wo_c   = (const float*)d_in[10];
  const float* bo_c   = (const float*)d_in[11];
  const float* ln_g   = (const float*)d_in[12];
  const float* ln_b   = (const float*)d_in[13];
  const float* gw1    = (const float*)d_in[14];
  const float* gb1    = (const float*)d_in[15];
  const float* W1a    = (const float*)d_in[16];
  const float* b1a    = (const float*)d_in[17];
  const float* W2a    = (const float*)d_in[18];
  const float* b2a    = (const float*)d_in[19];
  const float* gw2    = (const float*)d_in[20];
  const float* gb2    = (const float*)d_in[21];
  const float* W1b    = (const float*)d_in[22];
  const float* b1b    = (const float*)d_in[23];
  const float* W2b    = (const float*)d_in[24];
  const float* b2b    = (const float*)d_in[25];
  const float* Wout   = (const float*)d_in[26];
  const float* bout   = (const float*)d_in[27];

  float* w = (float*)d_ws;
  const long SZ = 1048576;            // NTOK*DM
  float* pos  = w;                    // 262144
  float* src  = pos  + 262144;
  float* t2s  = src  + SZ;
  float* tgtA = t2s  + SZ;
  float* dec  = tgtA + SZ;
  float* od   = dec  + SZ;
  float* od2  = od   + SZ;
  float* yg   = od2  + SZ;            // 2,097,152 fp32
  float* scoresA = yg + 2097152;      // 8192
  float* scoresB = scoresA + 8192;    // 8192
  // pre-split MoE weights: 8 planes x 2,097,152 u16 = 8,388,608 floats
  u16* wsp  = (u16*)(scoresB + 8192);
  u16* W1ah = wsp;             u16* W1al = wsp + 2097152;
  u16* W1bh = wsp + 4194304;   u16* W1bl = wsp + 6291456;
  u16* W2ah = wsp + 8388608;   u16* W2al = wsp + 10485760;
  u16* W2bh = wsp + 12582912;  u16* W2bl = wsp + 14680064;
  // overlay region R: 8,388,608 floats
  float* R   = scoresB + 8192 + 8388608;
  float* tok = R;                     // dead before q written
  float* q   = R;
  float* k   = R + SZ;                // also reused as t2c
  float* v   = R + 2*SZ;
  float* ao  = R + 3*SZ;
  u32*  hg   = (u32*)R;               // packed pairs (MoE phase; q..ao dead)
  float* rec = R;                     // final (hg dead)
  int* ip    = (int*)(R + 8388608);
  int* topiA = ip;                    // 8192
  int* topiB = ip + 8192;             // 8192
  int* map   = ip + 16384;            // 8192
  int* rposA = ip + 24576;            // 8192
  int* rposB = ip + 32768;            // 8192
  int* cnts  = ip + 40960;            // 4 sets * 8
  int* offsg = ip + 40992;            // 4 sets * 8

  dim3 blk(256);
  dim3 gDense(128, 4, 1);
  dim3 gQKV(128, 4, 3);
  dim3 gMoe1(128, 16, 8);
  dim3 gMoe2(128, 4, 8);

  zero_ints<<<1, 64, 0, stream>>>(cnts, 32);
  pos_kernel<<<NHW, DM, 0, stream>>>(pos);
  tin_kernel<<<(NTOK*NCIN + 255)/256, blk, 0, stream>>>(x, tok);

  tconv_kernel<<<dim3(32, 8, 8), blk, 0, stream>>>(W1a, W1ah, W1al, DM,   NDFF);
  tconv_kernel<<<dim3(32, 8, 8), blk, 0, stream>>>(W1b, W1bh, W1bl, DM,   NDFF);
  tconv_kernel<<<dim3(8, 32, 8), blk, 0, stream>>>(W2a, W2ah, W2al, NDFF, DM);
  tconv_kernel<<<dim3(8, 32, 8), blk, 0, stream>>>(W2b, W2bh, W2bl, NDFF, DM);

  // src = tok @ Wi^T + bi   (K=272)
  gemm_plain<<<gDense, blk, GEMM_SMEM, stream>>>(
      tok, NCIN, Wi, NCIN, bi, src, DM, NTOK, DM, NCIN);

  // self-attention (layer-invariant, hoisted): q=(le[s]+pos)Wq, k=(src+pos)Wk, v=src Wv
  gemm_qkv<<<gQKV, blk, GEMM_SMEM, stream>>>(
      le, 3, src, 2, src, pos, Wqkv_s, bqkv_s, q, k, v);
  attn_kernel<<<dim3(16,32), blk, 0, stream>>>(q, k, v, ao);
  gemm_plain<<<gDense, blk, GEMM_SMEM, stream>>>(
      ao, DM, Wo_s, DM, bo_s, t2s, DM, NTOK, DM, DM);

  const float* decIn = src;
  for (int i = 0; i < 2; i++){
    int* cntA = cnts + (i*2)*8;   int* offsA = offsg + (i*2)*8;
    int* cntB = cnts + (i*2+1)*8; int* offsB = offsg + (i*2+1)*8;

    add_ln_kernel<1><<<1024, blk, 0, stream>>>(le, t2s, ln_g + (4*i)*DM, ln_b + (4*i)*DM, tgtA);
    gemm_qkv<<<gQKV, blk, GEMM_SMEM, stream>>>(
        tgtA, 2, decIn, 2, decIn, pos, Wqkv_c, bqkv_c, q, k, v);
    attn_kernel<<<dim3(16,32), blk, 0, stream>>>(q, k, v, ao);
    gemm_plain<<<gDense, blk, GEMM_SMEM, stream>>>(
        ao, DM, Wo_c, DM, bo_c, k, DM, NTOK, DM, DM);     // t2c -> k (dead)
    add_ln_gate<<<1024, blk, 0, stream>>>(tgtA, k, ln_g + (4*i+1)*DM, ln_b + (4*i+1)*DM, od,
        gw1, gb1, scoresA, topiA, cntA);

    // ---- MoE a ----
    offs_assign<<<1, blk, 0, stream>>>(cntA, offsA, topiA, map, rposA);
    gemm_moe1<<<gMoe1, blk, GEMM_SMEM, stream>>>(od, W1ah, W1al, b1a, hg, map, cntA, offsA);
    gemm_moe2<<<gMoe2, blk, GEMM_SMEM, stream>>>(hg, W2ah, W2al, b2a, yg, cntA, offsA);
    moe_ln_kernel<true><<<1024, blk, 0, stream>>>(od, yg, scoresA, rposA,
        ln_g + (4*i+2)*DM, ln_b + (4*i+2)*DM, od2, gw2, gb2, scoresB, topiB, cntB);

    // ---- MoE b ----
    offs_assign<<<1, blk, 0, stream>>>(cntB, offsB, topiB, map, rposB);
    gemm_moe1<<<gMoe1, blk, GEMM_SMEM, stream>>>(od2, W1bh, W1bl, b1b, hg, map, cntB, offsB);
    gemm_moe2<<<gMoe2, blk, GEMM_SMEM, stream>>>(hg, W2bh, W2bl, b2b, yg, cntB, offsB);
    moe_ln_kernel<false><<<1024, blk, 0, stream>>>(od2, yg, scoresB, rposB,
        ln_g + (4*i+3)*DM, ln_b + (4*i+3)*DM, dec,
        nullptr, nullptr, nullptr, nullptr, nullptr);

    decIn = dec;
  }

  // rec = dec @ Wout^T + bout   [4096, 272]
  gemm_plain<<<dim3(128,5,1), blk, GEMM_SMEM, stream>>>(
      dec, DM, Wout, DM, bout, rec, NCIN, NTOK, NCIN, DM);
  tout_kernel<<<(NTOK*NCIN + 255)/256, blk, 0, stream>>>(rec, (float*)d_out);
}

// Round 8
// 1142.147 us; speedup vs baseline: 2.0986x; 1.2134x over previous
//
#include <hip/hip_runtime.h>

#define NHW 1024
#define NB 4
#define DM 256
#define NTOK 4096      // NHW * NB
#define NCIN 272
#define NDFF 1024

typedef unsigned short u16;
typedef unsigned int u32;
typedef __attribute__((ext_vector_type(8))) short s16x8;
typedef __attribute__((ext_vector_type(4))) float f32x4;

static const int GEMM_SMEM = (32+32+64+64)*56*2;   // 21504 B dynamic LDS

__device__ __forceinline__ float4 ld4(const float* p){ return *(const float4*)p; }
__device__ __forceinline__ void st4(float* p, float4 v){ *(float4*)p = v; }

// split fp32 -> bf16 hi + bf16 lo  (hi = RNE(x); lo = RNE(x - hi))
__device__ __forceinline__ void splitf(float x, u16& h, u16& l){
  u32 u = __float_as_uint(x);
  u32 hu = (u + (0x7FFFu + ((u >> 16) & 1u))) >> 16;
  h = (u16)hu;
  float hf = __uint_as_float(hu << 16);
  float r = x - hf;
  u32 v = __float_as_uint(r);
  v += 0x7FFFu + ((v >> 16) & 1u);
  l = (u16)(v >> 16);
}

// ---------------- positional embedding ----------------
__global__ void pos_kernel(float* __restrict__ pos){
  int s = blockIdx.x, d = threadIdx.x;
  int row = s >> 5, col = s & 31;
  float base = (d < 128) ? (float)(row + 1) : (float)(col + 1);
  float val = base / (32.0f + 1e-6f) * 6.2831853071795864f;
  int dd = (d < 128) ? d : d - 128;
  int mf = dd >> 1;
  float f = powf(10000.0f, (float)mf * (1.0f/64.0f));
  float a = val / f;
  pos[s*DM + d] = (dd & 1) ? cosf(a) : sinf(a);
}

// ---------------- transposes ----------------
__global__ void tin_kernel(const float* __restrict__ x, float* __restrict__ tok){
  int idx = blockIdx.x*256 + threadIdx.x;
  if (idx >= NTOK*NCIN) return;
  int c = idx % NCIN;
  int n = idx / NCIN;
  int s = n >> 2, b = n & 3;
  tok[idx] = x[((long)(b*NCIN + c))*NHW + s];
}
__global__ void tout_kernel(const float* __restrict__ rec, float* __restrict__ out){
  int idx = blockIdx.x*256 + threadIdx.x;
  if (idx >= NTOK*NCIN) return;
  int s = idx & (NHW-1);
  int bc = idx >> 10;
  int b = bc / NCIN, c = bc % NCIN;
  out[idx] = rec[((long)(s*NB + b))*NCIN + c];
}

// -------- weight transpose+split: in [K][N] fp32 -> hi/lo planes [N][K] bf16 --------
__global__ __launch_bounds__(256) void tconv_kernel(const float* __restrict__ in,
    u16* __restrict__ oh, u16* __restrict__ ol, int K, int N){
  __shared__ float tile[32][33];
  long base = (long)blockIdx.z * (long)K * (long)N;
  int k0 = blockIdx.y*32, n0 = blockIdx.x*32;
  int tx = threadIdx.x & 31, ty = threadIdx.x >> 5;   // ty 0..7
  #pragma unroll
  for (int i=0;i<32;i+=8)
    tile[ty+i][tx] = in[base + (long)(k0+ty+i)*N + n0+tx];
  __syncthreads();
  #pragma unroll
  for (int i=0;i<32;i+=8){
    float v = tile[tx][ty+i];
    u16 h,l; splitf(v,h,l);
    long o = base + (long)(n0+ty+i)*K + k0+tx;
    oh[o]=h; ol[o]=l;
  }
}

// -------- elementwise split (no transpose): [N][K] fp32 -> hi/lo planes --------
__global__ void wsplit_kernel(const float* __restrict__ in, u16* __restrict__ oh,
    u16* __restrict__ ol, int n){
  int i = blockIdx.x*256 + threadIdx.x;
  if (i < n){ u16 h,l; splitf(in[i],h,l); oh[i]=h; ol[i]=l; }
}

// ---------------- split-bf16 MFMA GEMM body (3-term) ----------------
// Tile 32x64, BK=32, 256 threads = 4 waves; wave computes 16x32.
// ASRC 0: A fp32. 1: A packed hi|lo u32. 2: A fp32 + pos[n>>2]. 3: A fp32 s-indexed + pos.
// B: pre-split hi/lo planes [N][ldb] u16 (always).
// CDST 0: C fp32. 1: C packed u32 pairs.
template<bool GROUPED, bool INDIRECT, int ASRC, bool RELU, int CDST>
__device__ __forceinline__ void sgemm_body(
    const void* __restrict__ Av, int lda,
    const float* __restrict__ pos,
    const u16* __restrict__ Bhp, const u16* __restrict__ Blp, int ldb,
    const float* __restrict__ bias,
    void* __restrict__ Cv, int ldc,
    int M, int N, int K,
    const int* __restrict__ map,
    const int* __restrict__ cnt,
    const int* __restrict__ offs,
    long strideB, int strideBias, int e)
{
  int rows = GROUPED ? cnt[e] : M;
  int bm = blockIdx.x, bn = blockIdx.y;
  if (bm*32 >= rows) return;
  int row0 = GROUPED ? offs[e] : 0;
  const float* Af = (const float*)Av;
  const u32*   Ap = (const u32*)Av;
  if (GROUPED){ Bhp += (long)e*strideB; Blp += (long)e*strideB; }
  const float* biasp = bias ? (GROUPED ? bias + (long)e*strideBias : bias) : nullptr;

  extern __shared__ u16 smem[];
  u16* Ah = smem;                 // 32*56
  u16* Al = Ah + 32*56;
  u16* Bh = Al + 32*56;           // 64*56
  u16* Bl = Bh + 64*56;

  int tid = threadIdx.x;
  int w = tid >> 6, ln = tid & 63;
  int wm = w >> 1, wn = w & 1;
  int lr = ln & 15, lh = ln >> 4;
  int srow = tid >> 2, sseg = tid & 3;

  int bgrow = bn*64 + srow;
  bool bok = bgrow < N;
  int agrow = bm*32 + srow;
  bool aok = (tid < 128) && (agrow < rows);
  long arow = 0;
  if (aok) arow = INDIRECT ? (long)map[row0 + agrow] : (long)(row0 + agrow);

  const f32x4 z4 = {0.f,0.f,0.f,0.f};
  f32x4 acc0 = z4, acc1 = z4;
  const s16x8 z8 = {0,0,0,0,0,0,0,0};

  for (int k0 = 0; k0 < K; k0 += 32){
    int kk = k0 + sseg*8;
    bool kok = kk < K;                 // K % 8 == 0 always
    s16x8 hv = z8, lv = z8;
    if (bok && kok){
      hv = *(const s16x8*)&Bhp[(long)bgrow*ldb + kk];
      lv = *(const s16x8*)&Blp[(long)bgrow*ldb + kk];
    }
    *(s16x8*)&Bh[srow*56 + sseg*8] = hv;
    *(s16x8*)&Bl[srow*56 + sseg*8] = lv;
    if (tid < 128){
      hv = z8; lv = z8;
      if (aok && kok){
        if (ASRC == 1){
          uint4 p0 = *(const uint4*)&Ap[arow*lda + kk];
          uint4 p1 = *(const uint4*)&Ap[arow*lda + kk + 4];
          u32 ws[8] = {p0.x,p0.y,p0.z,p0.w,p1.x,p1.y,p1.z,p1.w};
          #pragma unroll
          for (int t=0;t<8;t++){ hv[t]=(short)(ws[t]&0xFFFFu); lv[t]=(short)(ws[t]>>16); }
        } else {
          long aoff = (ASRC==3 ? (long)(arow>>2) : arow)*lda + kk;
          float4 x0 = ld4(&Af[aoff]);
          float4 x1 = ld4(&Af[aoff + 4]);
          if (ASRC==2 || ASRC==3){
            long poff = (long)(arow>>2)*DM + kk;
            float4 p0 = ld4(&pos[poff]);
            float4 p1 = ld4(&pos[poff + 4]);
            x0.x+=p0.x; x0.y+=p0.y; x0.z+=p0.z; x0.w+=p0.w;
            x1.x+=p1.x; x1.y+=p1.y; x1.z+=p1.z; x1.w+=p1.w;
          }
          float xs[8] = {x0.x,x0.y,x0.z,x0.w,x1.x,x1.y,x1.z,x1.w};
          #pragma unroll
          for (int t=0;t<8;t++){ u16 hh,ll; splitf(xs[t],hh,ll); hv[t]=(short)hh; lv[t]=(short)ll; }
        }
      }
      *(s16x8*)&Ah[srow*56 + sseg*8] = hv;
      *(s16x8*)&Al[srow*56 + sseg*8] = lv;
    }
    __syncthreads();
    s16x8 a0h = *(const s16x8*)&Ah[(wm*16 + lr)*56 + lh*8];
    s16x8 a0l = *(const s16x8*)&Al[(wm*16 + lr)*56 + lh*8];
    s16x8 b0h = *(const s16x8*)&Bh[(wn*32      + lr)*56 + lh*8];
    s16x8 b1h = *(const s16x8*)&Bh[(wn*32 + 16 + lr)*56 + lh*8];
    s16x8 b0l = *(const s16x8*)&Bl[(wn*32      + lr)*56 + lh*8];
    s16x8 b1l = *(const s16x8*)&Bl[(wn*32 + 16 + lr)*56 + lh*8];
    acc0 = __builtin_amdgcn_mfma_f32_16x16x32_bf16(a0h, b0h, acc0, 0,0,0);
    acc1 = __builtin_amdgcn_mfma_f32_16x16x32_bf16(a0h, b1h, acc1, 0,0,0);
    acc0 = __builtin_amdgcn_mfma_f32_16x16x32_bf16(a0h, b0l, acc0, 0,0,0);
    acc1 = __builtin_amdgcn_mfma_f32_16x16x32_bf16(a0h, b1l, acc1, 0,0,0);
    acc0 = __builtin_amdgcn_mfma_f32_16x16x32_bf16(a0l, b0h, acc0, 0,0,0);
    acc1 = __builtin_amdgcn_mfma_f32_16x16x32_bf16(a0l, b1h, acc1, 0,0,0);
    __syncthreads();
  }

  int c0 = bn*64 + wn*32 + lr;
  int c1 = c0 + 16;
  float bv0 = (biasp && c0 < N) ? biasp[c0] : 0.f;
  float bv1 = (biasp && c1 < N) ? biasp[c1] : 0.f;
  int rbase = bm*32 + wm*16 + lh*4;
  auto stc = [&](int gr, int gc, float vv){
    if (gr < rows && gc < N){
      float t = RELU ? fmaxf(vv, 0.f) : vv;
      if (CDST == 1){
        u16 h,l; splitf(t,h,l);
        ((u32*)Cv)[(long)(row0+gr)*ldc + gc] = (u32)h | ((u32)l << 16);
      } else {
        ((float*)Cv)[(long)(row0+gr)*ldc + gc] = t;
      }
    }
  };
  #pragma unroll
  for (int r = 0; r < 4; r++){
    stc(rbase + r, c0, acc0[r] + bv0);
    stc(rbase + r, c1, acc1[r] + bv1);
  }
}

// ---- named GEMM wrappers ----
__global__ __launch_bounds__(256) void gemm_plain(const float* A, int lda,
    const u16* Bh_, const u16* Bl_, int ldb, const float* bias, float* C, int ldc,
    int M, int N, int K){
  sgemm_body<false,false,0,false,0>(A, lda, nullptr, Bh_, Bl_, ldb, bias, C, ldc,
      M, N, K, nullptr, nullptr, nullptr, 0, 0, 0);
}

__global__ __launch_bounds__(256) void gemm_qkv(const float* Aq, int mq,
    const float* Ak, int mk, const float* Avv, const float* pos,
    const u16* Bwh, const u16* Bwl, const float* bias, float* Cq, float* Ck, float* Cvv){
  int z = blockIdx.z;
  const float* A = z==0 ? Aq : (z==1 ? Ak : Avv);
  float* C = z==0 ? Cq : (z==1 ? Ck : Cvv);
  const u16* Bph = Bwh + (long)z*256*DM;
  const u16* Bpl = Bwl + (long)z*256*DM;
  const float* bp = bias + z*256;
  int mode = z==0 ? mq : (z==1 ? mk : 0);
  if (mode == 3)
    sgemm_body<false,false,3,false,0>(A, DM, pos, Bph, Bpl, DM, bp, C, DM,
        NTOK, DM, DM, nullptr, nullptr, nullptr, 0, 0, 0);
  else if (mode == 2)
    sgemm_body<false,false,2,false,0>(A, DM, pos, Bph, Bpl, DM, bp, C, DM,
        NTOK, DM, DM, nullptr, nullptr, nullptr, 0, 0, 0);
  else
    sgemm_body<false,false,0,false,0>(A, DM, pos, Bph, Bpl, DM, bp, C, DM,
        NTOK, DM, DM, nullptr, nullptr, nullptr, 0, 0, 0);
}

__global__ __launch_bounds__(256) void gemm_moe1(const float* A, const u16* Bh_, const u16* Bl_,
    const float* bias, u32* C, const int* map, const int* cnt, const int* offs){
  sgemm_body<true,true,0,true,1>(A, DM, nullptr, Bh_, Bl_, DM, bias, C, NDFF,
      0, NDFF, DM, map, cnt, offs, 262144L, NDFF, blockIdx.z);
}

__global__ __launch_bounds__(256) void gemm_moe2(const u32* A, const u16* Bh_, const u16* Bl_,
    const float* bias, float* C, const int* cnt, const int* offs){
  sgemm_body<true,false,1,false,0>(A, NDFF, nullptr, Bh_, Bl_, NDFF, bias, C, DM,
      0, DM, NDFF, nullptr, cnt, offs, 262144L, DM, blockIdx.z);
}

// ---------------- MFMA flash attention, split-bf16, dh=32, S=T=1024 ----------------
// grid (16 q-tiles of 64 rows, 32 bh); block 256 = 4 waves, wave owns 16 q-rows.
__global__ __launch_bounds__(256) void attn_mfma(const float* __restrict__ Q,
    const float* __restrict__ Kb, const float* __restrict__ Vb, float* __restrict__ O)
{
  __shared__ u16 Kh[64*40], Kl[64*40];      // K-tile [key][dh], stride 40
  __shared__ u16 Vh[32*72], Vl[32*72];      // V^T-tile [dh][key], stride 72
  __shared__ u16 Ph[4][16*72], Pl[4][16*72];// per-wave P [q][key], stride 72

  int qt = blockIdx.x, bh = blockIdx.y;
  int b = bh >> 3, h = bh & 7;
  int tid = threadIdx.x;
  int wv = tid >> 6, ln = tid & 63;
  int lr = ln & 15, lh = ln >> 4;
  const float scale = 0.17677669529663687f;  // 1/sqrt(32)

  // Q fragment: wave wv rows, A-frag row=lr, k-octet lh
  s16x8 qh, ql;
  {
    long qrow = ((long)((qt*64 + wv*16 + lr)*NB + b))*DM + h*32 + lh*8;
    float4 x0 = ld4(&Q[qrow]);
    float4 x1 = ld4(&Q[qrow + 4]);
    float xs[8] = {x0.x,x0.y,x0.z,x0.w,x1.x,x1.y,x1.z,x1.w};
    #pragma unroll
    for (int t=0;t<8;t++){
      u16 hh,ll; splitf(xs[t]*scale,hh,ll);
      qh[t]=(short)hh; ql[t]=(short)ll;
    }
  }

  const f32x4 z4 = {0.f,0.f,0.f,0.f};
  f32x4 oacc0 = z4, oacc1 = z4;
  float m[4]  = {-1e30f,-1e30f,-1e30f,-1e30f};
  float lp[4] = {0.f,0.f,0.f,0.f};

  for (int kt = 0; kt < 16; kt++){
    __syncthreads();
    // stage K-tile: thread -> (key = tid>>2, octet = tid&3)
    {
      int key = tid >> 2, oct = tid & 3;
      long g = ((long)((kt*64 + key)*NB + b))*DM + h*32 + oct*8;
      float4 x0 = ld4(&Kb[g]);
      float4 x1 = ld4(&Kb[g + 4]);
      float xs[8] = {x0.x,x0.y,x0.z,x0.w,x1.x,x1.y,x1.z,x1.w};
      s16x8 hv, lv;
      #pragma unroll
      for (int t=0;t<8;t++){ u16 hh,ll; splitf(xs[t],hh,ll); hv[t]=(short)hh; lv[t]=(short)ll; }
      *(s16x8*)&Kh[key*40 + oct*8] = hv;
      *(s16x8*)&Kl[key*40 + oct*8] = lv;
    }
    // stage V-tile transposed: 2 float4 per thread
    #pragma unroll
    for (int it=0; it<2; it++){
      int idx = tid + it*256;
      int key = idx >> 3, d4 = (idx & 7) << 2;
      long g = ((long)((kt*64 + key)*NB + b))*DM + h*32 + d4;
      float4 x = ld4(&Vb[g]);
      u16 hh,ll;
      splitf(x.x,hh,ll); Vh[(d4+0)*72 + key]=hh; Vl[(d4+0)*72 + key]=ll;
      splitf(x.y,hh,ll); Vh[(d4+1)*72 + key]=hh; Vl[(d4+1)*72 + key]=ll;
      splitf(x.z,hh,ll); Vh[(d4+2)*72 + key]=hh; Vl[(d4+2)*72 + key]=ll;
      splitf(x.w,hh,ll); Vh[(d4+3)*72 + key]=hh; Vl[(d4+3)*72 + key]=ll;
    }
    __syncthreads();

    // S = Q K^T : 4 key-subtiles of 16
    f32x4 sacc[4];
    #pragma unroll
    for (int s16t=0; s16t<4; s16t++){
      s16x8 kbh = *(const s16x8*)&Kh[(s16t*16 + lr)*40 + lh*8];
      s16x8 kbl = *(const s16x8*)&Kl[(s16t*16 + lr)*40 + lh*8];
      f32x4 a = z4;
      a = __builtin_amdgcn_mfma_f32_16x16x32_bf16(qh, kbh, a, 0,0,0);
      a = __builtin_amdgcn_mfma_f32_16x16x32_bf16(qh, kbl, a, 0,0,0);
      a = __builtin_amdgcn_mfma_f32_16x16x32_bf16(ql, kbh, a, 0,0,0);
      sacc[s16t] = a;
    }
    // row-max over this tile: in-reg over 4 subtiles, then shfl over the 16-lane col group
    float tm[4];
    #pragma unroll
    for (int r=0;r<4;r++)
      tm[r] = fmaxf(fmaxf(sacc[0][r],sacc[1][r]), fmaxf(sacc[2][r],sacc[3][r]));
    #pragma unroll
    for (int mask=1; mask<=8; mask<<=1){
      #pragma unroll
      for (int r=0;r<4;r++) tm[r] = fmaxf(tm[r], __shfl_xor(tm[r], mask));
    }
    // online rescale (exp(0)==1 exactly when max unchanged)
    #pragma unroll
    for (int r=0;r<4;r++){
      float mn = fmaxf(m[r], tm[r]);
      float al = __expf(m[r] - mn);
      m[r] = mn;
      lp[r] *= al;
      oacc0[r] *= al;
      oacc1[r] *= al;
    }
    // p = exp(s - m); accumulate partial l; write P (split) to per-wave LDS
    #pragma unroll
    for (int s16t=0; s16t<4; s16t++){
      #pragma unroll
      for (int r=0;r<4;r++){
        float p = __expf(sacc[s16t][r] - m[r]);
        lp[r] += p;
        u16 hh,ll; splitf(p,hh,ll);
        int off = (lh*4 + r)*72 + s16t*16 + lr;
        Ph[wv][off] = hh;
        Pl[wv][off] = ll;
      }
    }
    // PV: A = P [16q x 32keys] x2 K-steps; B = V^T [16dh x 32keys] x2 dh-tiles; 3-term
    #pragma unroll
    for (int ks=0; ks<2; ks++){
      s16x8 pah = *(const s16x8*)&Ph[wv][lr*72 + ks*32 + lh*8];
      s16x8 pal = *(const s16x8*)&Pl[wv][lr*72 + ks*32 + lh*8];
      s16x8 vh0 = *(const s16x8*)&Vh[lr*72      + ks*32 + lh*8];
      s16x8 vl0 = *(const s16x8*)&Vl[lr*72      + ks*32 + lh*8];
      s16x8 vh1 = *(const s16x8*)&Vh[(16+lr)*72 + ks*32 + lh*8];
      s16x8 vl1 = *(const s16x8*)&Vl[(16+lr)*72 + ks*32 + lh*8];
      oacc0 = __builtin_amdgcn_mfma_f32_16x16x32_bf16(pah, vh0, oacc0, 0,0,0);
      oacc0 = __builtin_amdgcn_mfma_f32_16x16x32_bf16(pah, vl0, oacc0, 0,0,0);
      oacc0 = __builtin_amdgcn_mfma_f32_16x16x32_bf16(pal, vh0, oacc0, 0,0,0);
      oacc1 = __builtin_amdgcn_mfma_f32_16x16x32_bf16(pah, vh1, oacc1, 0,0,0);
      oacc1 = __builtin_amdgcn_mfma_f32_16x16x32_bf16(pah, vl1, oacc1, 0,0,0);
      oacc1 = __builtin_amdgcn_mfma_f32_16x16x32_bf16(pal, vh1, oacc1, 0,0,0);
    }
  }
  // final l reduction across the 16-lane col group
  #pragma unroll
  for (int mask=1; mask<=8; mask<<=1){
    #pragma unroll
    for (int r=0;r<4;r++) lp[r] += __shfl_xor(lp[r], mask);
  }
  // write O: row q = lh*4+r, col dh = lr (+16)
  #pragma unroll
  for (int r=0;r<4;r++){
    float inv = 1.f/lp[r];
    int q = qt*64 + wv*16 + lh*4 + r;
    long orow = ((long)(q*NB + b))*DM + h*32;
    O[orow + lr]      = oacc0[r]*inv;
    O[orow + 16 + lr] = oacc1[r]*inv;
  }
}

// ---------------- LN / gate helpers ----------------
__device__ __forceinline__ float wave_sum(float v){
  #pragma unroll
  for (int m=1; m<64; m<<=1) v += __shfl_xor(v, m);
  return v;
}

__device__ __forceinline__ float4 ln_finish(float4 a, const float* g, const float* beta, int lane){
  float sum = wave_sum(a.x+a.y+a.z+a.w);
  float sq  = wave_sum(a.x*a.x + a.y*a.y + a.z*a.z + a.w*a.w);
  float mean = sum * (1.f/DM);
  float var  = sq * (1.f/DM) - mean*mean;
  float inv = 1.0f / sqrtf(var + 1e-5f);
  float4 gg = ld4(&g[lane*4]);
  float4 bb = ld4(&beta[lane*4]);
  float4 ov;
  ov.x = (a.x-mean)*inv*gg.x + bb.x;
  ov.y = (a.y-mean)*inv*gg.y + bb.y;
  ov.z = (a.z-mean)*inv*gg.z + bb.z;
  ov.w = (a.w-mean)*inv*gg.w + bb.w;
  return ov;
}

__device__ __forceinline__ void gate_from_regs(float4 ov, int row, int lane,
    const float* GW, const float* GB, float* scores, int* topi, int* cnt){
  float lg[8];
  #pragma unroll
  for (int e=0; e<8; e++){
    float4 wv = ld4(&GW[e*DM + lane*4]);
    lg[e] = ov.x*wv.x + ov.y*wv.y + ov.z*wv.z + ov.w*wv.w;
  }
  #pragma unroll
  for (int mask=1; mask<64; mask<<=1){
    #pragma unroll
    for (int e=0; e<8; e++) lg[e] += __shfl_xor(lg[e], mask);
  }
  #pragma unroll
  for (int e=0; e<8; e++) lg[e] += GB[e];
  int i0 = 0; float v0 = lg[0];
  #pragma unroll
  for (int e=1; e<8; e++) if (lg[e] > v0){ v0 = lg[e]; i0 = e; }
  int i1 = -1; float v1 = -1e30f;
  #pragma unroll
  for (int e=0; e<8; e++) if (e != i0 && lg[e] > v1){ v1 = lg[e]; i1 = e; }
  if (lane == 0){
    float ee = expf(v1 - v0);
    float inv = 1.f/(1.f + ee);
    scores[row*2]   = inv;
    scores[row*2+1] = ee*inv;
    topi[row*2]   = i0;
    topi[row*2+1] = i1;
    atomicAdd(&cnt[i0], 1);
    atomicAdd(&cnt[i1], 1);
  }
}

template<int AMODE>
__global__ __launch_bounds__(256) void add_ln_kernel(const float* __restrict__ A,
    const float* __restrict__ Bv, const float* __restrict__ g, const float* __restrict__ beta,
    float* __restrict__ out)
{
  int row = blockIdx.x*4 + (threadIdx.x >> 6);
  int lane = threadIdx.x & 63;
  const float* ap = A + (AMODE ? (long)(row>>2)*DM : (long)row*DM);
  float4 a = ld4(&ap[lane*4]);
  float4 b = ld4(&Bv[(long)row*DM + lane*4]);
  a.x+=b.x; a.y+=b.y; a.z+=b.z; a.w+=b.w;
  float4 ov = ln_finish(a, g, beta, lane);
  st4(&out[(long)row*DM + lane*4], ov);
}

__global__ __launch_bounds__(256) void add_ln_gate(const float* __restrict__ A,
    const float* __restrict__ Bv, const float* __restrict__ g, const float* __restrict__ beta,
    float* __restrict__ out, const float* __restrict__ GW, const float* __restrict__ GB,
    float* __restrict__ scores, int* __restrict__ topi, int* __restrict__ cnt)
{
  int row = blockIdx.x*4 + (threadIdx.x >> 6);
  int lane = threadIdx.x & 63;
  float4 a = ld4(&A[(long)row*DM + lane*4]);
  float4 b = ld4(&Bv[(long)row*DM + lane*4]);
  a.x+=b.x; a.y+=b.y; a.z+=b.z; a.w+=b.w;
  float4 ov = ln_finish(a, g, beta, lane);
  st4(&out[(long)row*DM + lane*4], ov);
  gate_from_regs(ov, row, lane, GW, GB, scores, topi, cnt);
}

template<bool GATE>
__global__ __launch_bounds__(256) void moe_ln_kernel(const float* __restrict__ base,
    const float* __restrict__ yg, const float* __restrict__ scores, const int* __restrict__ rpos,
    const float* __restrict__ g, const float* __restrict__ beta, float* __restrict__ out,
    const float* __restrict__ GW, const float* __restrict__ GB,
    float* __restrict__ scores2, int* __restrict__ topi2, int* __restrict__ cnt2)
{
  int row = blockIdx.x*4 + (threadIdx.x >> 6);
  int lane = threadIdx.x & 63;
  float s0 = scores[row*2], s1 = scores[row*2+1];
  int r0 = rpos[row*2], r1 = rpos[row*2+1];
  float4 a  = ld4(&base[(long)row*DM + lane*4]);
  float4 y0 = ld4(&yg[(long)r0*DM + lane*4]);
  float4 y1 = ld4(&yg[(long)r1*DM + lane*4]);
  a.x += s0*y0.x + s1*y1.x;
  a.y += s0*y0.y + s1*y1.y;
  a.z += s0*y0.z + s1*y1.z;
  a.w += s0*y0.w + s1*y1.w;
  float4 ov = ln_finish(a, g, beta, lane);
  st4(&out[(long)row*DM + lane*4], ov);
  if (GATE) gate_from_regs(ov, row, lane, GW, GB, scores2, topi2, cnt2);
}

__global__ void offs_assign(const int* __restrict__ cnt, int* __restrict__ offs_g,
    const int* __restrict__ topi, int* __restrict__ map, int* __restrict__ rpos)
{
  __shared__ int offs[8];
  __shared__ int c2[8];
  if (threadIdx.x == 0){
    int o = 0;
    #pragma unroll
    for (int e=0; e<8; e++){ offs[e] = o; o += cnt[e]; }
  }
  if (threadIdx.x < 8) c2[threadIdx.x] = 0;
  __syncthreads();
  for (int n = threadIdx.x; n < NTOK; n += 256){
    #pragma unroll
    for (int j=0; j<2; j++){
      int e = topi[n*2+j];
      int slot = atomicAdd(&c2[e], 1);
      int r = offs[e] + slot;
      map[r] = n;
      rpos[n*2+j] = r;
    }
  }
  if (threadIdx.x < 8) offs_g[threadIdx.x] = offs[threadIdx.x];
}

__global__ void zero_ints(int* p, int n){
  int i = blockIdx.x*256 + threadIdx.x;
  if (i < n) p[i] = 0;
}

// =================================================================
extern "C" void kernel_launch(void* const* d_in, const int* in_sizes, int n_in,
                              void* d_out, int out_size, void* d_ws, size_t ws_size,
                              hipStream_t stream)
{
  const float* x      = (const float*)d_in[0];
  const float* Wi     = (const float*)d_in[1];
  const float* bi     = (const float*)d_in[2];
  const float* le     = (const float*)d_in[3];
  const float* Wqkv_s = (const float*)d_in[4];
  const float* bqkv_s = (const float*)d_in[5];
  const float* Wo_s   = (const float*)d_in[6];
  const float* bo_s   = (const float*)d_in[7];
  const float* Wqkv_c = (const float*)d_in[8];
  const float* bqkv_c = (const float*)d_in[9];
  const float* Wo_c   = (const float*)d_in[10];
  const float* bo_c   = (const float*)d_in[11];
  const float* ln_g   = (const float*)d_in[12];
  const float* ln_b   = (const float*)d_in[13];
  const float* gw1    = (const float*)d_in[14];
  const float* gb1    = (const float*)d_in[15];
  const float* W1a    = (const float*)d_in[16];
  const float* b1a    = (const float*)d_in[17];
  const float* W2a    = (const float*)d_in[18];
  const float* b2a    = (const float*)d_in[19];
  const float* gw2    = (const float*)d_in[20];
  const float* gb2    = (const float*)d_in[21];
  const float* W1b    = (const float*)d_in[22];
  const float* b1b    = (const float*)d_in[23];
  const float* W2b    = (const float*)d_in[24];
  const float* b2b    = (const float*)d_in[25];
  const float* Wout   = (const float*)d_in[26];
  const float* bout   = (const float*)d_in[27];

  float* w = (float*)d_ws;
  const long SZ = 1048576;            // NTOK*DM
  float* pos  = w;                    // 262144
  float* src  = pos  + 262144;
  float* t2s  = src  + SZ;
  float* tgtA = t2s  + SZ;
  float* dec  = tgtA + SZ;
  float* od   = dec;                  // ALIAS: od and dec have disjoint live ranges
  float* od2  = dec  + SZ;
  float* yg   = od2  + SZ;            // 2,097,152 fp32
  float* scoresA = yg + 2097152;      // 8192
  float* scoresB = scoresA + 8192;    // 8192
  // pre-split MoE weights: 8 planes x 2,097,152 u16 = 8,388,608 floats
  u16* wsp  = (u16*)(scoresB + 8192);
  u16* W1ah = wsp;             u16* W1al = wsp + 2097152;
  u16* W1bh = wsp + 4194304;   u16* W1bl = wsp + 6291456;
  u16* W2ah = wsp + 8388608;   u16* W2al = wsp + 10485760;
  u16* W2bh = wsp + 12582912;  u16* W2bl = wsp + 14680064;
  // pre-split dense weights (u16), 1,327,104 total = 663,552 floats
  u16* dwp  = wsp + 16777216;
  u16* Wih   = dwp;            u16* Wil   = dwp + 69632;     // 256x272
  u16* Wqsh  = dwp + 139264;   u16* Wqsl  = dwp + 335872;    // 768x256
  u16* Wosh  = dwp + 532480;   u16* Wosl  = dwp + 598016;    // 256x256
  u16* Wqch  = dwp + 663552;   u16* Wqcl  = dwp + 860160;    // 768x256
  u16* Woch  = dwp + 1056768;  u16* Wocl  = dwp + 1122304;   // 256x256
  u16* Wouth = dwp + 1187840;  u16* Woutl = dwp + 1257472;   // 272x256
  // overlay region R: 8,388,608 floats
  float* R   = (float*)(dwp + 1327104);
  float* tok = R;                     // dead before q written
  float* q   = R;
  float* k   = R + SZ;                // also reused as t2c
  float* v   = R + 2*SZ;
  float* ao  = R + 3*SZ;
  u32*  hg   = (u32*)R;               // packed pairs (MoE phase; q..ao dead)
  float* rec = R;                     // final (hg dead)
  int* ip    = (int*)(R + 8388608);
  int* topiA = ip;                    // 8192
  int* topiB = ip + 8192;             // 8192
  int* map   = ip + 16384;            // 8192
  int* rposA = ip + 24576;            // 8192
  int* rposB = ip + 32768;            // 8192
  int* cnts  = ip + 40960;            // 4 sets * 8
  int* offsg = ip + 40992;            // 4 sets * 8

  dim3 blk(256);
  dim3 gDense(128, 4, 1);
  dim3 gQKV(128, 4, 3);
  dim3 gMoe1(128, 16, 8);
  dim3 gMoe2(128, 4, 8);
  dim3 gAttn(16, 32);

  zero_ints<<<1, 64, 0, stream>>>(cnts, 32);
  pos_kernel<<<NHW, DM, 0, stream>>>(pos);
  tin_kernel<<<(NTOK*NCIN + 255)/256, blk, 0, stream>>>(x, tok);

  // one-time weight prep
  tconv_kernel<<<dim3(32, 8, 8), blk, 0, stream>>>(W1a, W1ah, W1al, DM,   NDFF);
  tconv_kernel<<<dim3(32, 8, 8), blk, 0, stream>>>(W1b, W1bh, W1bl, DM,   NDFF);
  tconv_kernel<<<dim3(8, 32, 8), blk, 0, stream>>>(W2a, W2ah, W2al, NDFF, DM);
  tconv_kernel<<<dim3(8, 32, 8), blk, 0, stream>>>(W2b, W2bh, W2bl, NDFF, DM);
  wsplit_kernel<<<272, blk, 0, stream>>>(Wi,     Wih,   Wil,   69632);
  wsplit_kernel<<<768, blk, 0, stream>>>(Wqkv_s, Wqsh,  Wqsl,  196608);
  wsplit_kernel<<<256, blk, 0, stream>>>(Wo_s,   Wosh,  Wosl,  65536);
  wsplit_kernel<<<768, blk, 0, stream>>>(Wqkv_c, Wqch,  Wqcl,  196608);
  wsplit_kernel<<<256, blk, 0, stream>>>(Wo_c,   Woch,  Wocl,  65536);
  wsplit_kernel<<<272, blk, 0, stream>>>(Wout,   Wouth, Woutl, 69632);

  // src = tok @ Wi^T + bi   (K=272)
  gemm_plain<<<gDense, blk, GEMM_SMEM, stream>>>(
      tok, NCIN, Wih, Wil, NCIN, bi, src, DM, NTOK, DM, NCIN);

  // self-attention (layer-invariant, hoisted): q=(le[s]+pos)Wq, k=(src+pos)Wk, v=src Wv
  gemm_qkv<<<gQKV, blk, GEMM_SMEM, stream>>>(
      le, 3, src, 2, src, pos, Wqsh, Wqsl, bqkv_s, q, k, v);
  attn_mfma<<<gAttn, blk, 0, stream>>>(q, k, v, ao);
  gemm_plain<<<gDense, blk, GEMM_SMEM, stream>>>(
      ao, DM, Wosh, Wosl, DM, bo_s, t2s, DM, NTOK, DM, DM);

  const float* decIn = src;
  for (int i = 0; i < 2; i++){
    int* cntA = cnts + (i*2)*8;   int* offsA = offsg + (i*2)*8;
    int* cntB = cnts + (i*2+1)*8; int* offsB = offsg + (i*2+1)*8;

    add_ln_kernel<1><<<1024, blk, 0, stream>>>(le, t2s, ln_g + (4*i)*DM, ln_b + (4*i)*DM, tgtA);
    gemm_qkv<<<gQKV, blk, GEMM_SMEM, stream>>>(
        tgtA, 2, decIn, 2, decIn, pos, Wqch, Wqcl, bqkv_c, q, k, v);
    attn_mfma<<<gAttn, blk, 0, stream>>>(q, k, v, ao);
    gemm_plain<<<gDense, blk, GEMM_SMEM, stream>>>(
        ao, DM, Woch, Wocl, DM, bo_c, k, DM, NTOK, DM, DM);   // t2c -> k (dead)
    add_ln_gate<<<1024, blk, 0, stream>>>(tgtA, k, ln_g + (4*i+1)*DM, ln_b + (4*i+1)*DM, od,
        gw1, gb1, scoresA, topiA, cntA);

    // ---- MoE a ----
    offs_assign<<<1, blk, 0, stream>>>(cntA, offsA, topiA, map, rposA);
    gemm_moe1<<<gMoe1, blk, GEMM_SMEM, stream>>>(od, W1ah, W1al, b1a, hg, map, cntA, offsA);
    gemm_moe2<<<gMoe2, blk, GEMM_SMEM, stream>>>(hg, W2ah, W2al, b2a, yg, cntA, offsA);
    moe_ln_kernel<true><<<1024, blk, 0, stream>>>(od, yg, scoresA, rposA,
        ln_g + (4*i+2)*DM, ln_b + (4*i+2)*DM, od2, gw2, gb2, scoresB, topiB, cntB);

    // ---- MoE b ----
    offs_assign<<<1, blk, 0, stream>>>(cntB, offsB, topiB, map, rposB);
    gemm_moe1<<<gMoe1, blk, GEMM_SMEM, stream>>>(od2, W1bh, W1bl, b1b, hg, map, cntB, offsB);
    gemm_moe2<<<gMoe2, blk, GEMM_SMEM, stream>>>(hg, W2bh, W2bl, b2b, yg, cntB, offsB);
    moe_ln_kernel<false><<<1024, blk, 0, stream>>>(od2, yg, scoresB, rposB,
        ln_g + (4*i+3)*DM, ln_b + (4*i+3)*DM, dec,
        nullptr, nullptr, nullptr, nullptr, nullptr);

    decIn = dec;
  }

  // rec = dec @ Wout^T + bout   [4096, 272]
  gemm_plain<<<dim3(128,5,1), blk, GEMM_SMEM, stream>>>(
      dec, DM, Wouth, Woutl, DM, bout, rec, NCIN, NTOK, NCIN, DM);
  tout_kernel<<<(NTOK*NCIN + 255)/256, blk, 0, stream>>>(rec, (float*)d_out);
}